// Round 8
// baseline (1042.257 us; speedup 1.0000x reference)
//
#include <hip/hip_runtime.h>
#include <cstdint>

#define GXD 480
#define GYD 360
#define NHD 32
#define NPTS 120000
#define MPAD 120064           // NPTS padded to multiple of 128
#define SEGR 129600           // 360*360 possible ids
#define NSEG (GXD*GYD)        // 172800
#define EPSB 1e-5f

using short8 = __attribute__((ext_vector_type(8))) short;   // 8 bf16 in 4 VGPRs
using f32x4  = __attribute__((ext_vector_type(4))) float;   // MFMA accumulator

// ---- bf16 helpers ----
__device__ __forceinline__ float bf2f(unsigned short u) {
    return __uint_as_float(((unsigned int)u) << 16);
}
__device__ __forceinline__ unsigned short f2bf(float f) {
    unsigned int u = __float_as_uint(f);
    u += 0x7fffu + ((u >> 16) & 1u);   // round-to-nearest-even
    return (unsigned short)(u >> 16);
}
__device__ __forceinline__ unsigned int bnrelu_pack(unsigned int wv, float sc0, float sh0,
                                                    float sc1, float sh1)
{
    float lo = fmaxf(fmaf(bf2f((unsigned short)(wv & 0xffffu)), sc0, sh0), 0.f);
    float hi = fmaxf(fmaf(bf2f((unsigned short)(wv >> 16)), sc1, sh1), 0.f);
    return (unsigned int)f2bf(lo) | ((unsigned int)f2bf(hi) << 16);
}

// ---- async global->LDS, 16B per lane (dest must be wave-uniform base + lane*16) ----
__device__ __forceinline__ void async16(const unsigned short* g, unsigned short* l)
{
    __builtin_amdgcn_global_load_lds(
        (const __attribute__((address_space(1))) unsigned int*)g,
        (__attribute__((address_space(3))) unsigned int*)l, 16, 0, 0);
}

// ---- bn0 stats ----
__global__ __launch_bounds__(256) void bn0_stats_kernel(
    const float* __restrict__ fea, float* __restrict__ s0, float* __restrict__ q0)
{
    float s[7] = {0,0,0,0,0,0,0}, q[7] = {0,0,0,0,0,0,0};
    for (int p = blockIdx.x * 256 + threadIdx.x; p < NPTS; p += gridDim.x * 256) {
        const float* r = fea + (size_t)p * 7;
#pragma unroll
        for (int f = 0; f < 7; ++f) { float v = r[f]; s[f] += v; q[f] += v * v; }
    }
    __shared__ float red[256];
    int t = threadIdx.x;
#pragma unroll
    for (int f = 0; f < 7; ++f) {
        red[t] = s[f]; __syncthreads();
        for (int o = 128; o > 0; o >>= 1) {
            if (t < o) red[t] += red[t + o];
            __syncthreads();
        }
        if (t == 0) atomicAdd(&s0[f], red[0]);
        __syncthreads();
        red[t] = q[f]; __syncthreads();
        for (int o = 128; o > 0; o >>= 1) {
            if (t < o) red[t] += red[t + o];
            __syncthreads();
        }
        if (t == 0) atomicAdd(&q0[f], red[0]);
        __syncthreads();
    }
}

// ---- fold bn0 into W1 ----
__global__ void prep0_kernel(const float* __restrict__ s0, const float* __restrict__ q0,
                             const float* __restrict__ g0, const float* __restrict__ b0,
                             const float* __restrict__ W1, const float* __restrict__ b1,
                             float* __restrict__ W1p, float* __restrict__ b1p)
{
    __shared__ float sc[7], sh[7];
    int t = threadIdx.x;
    if (t < 7) {
        float m = s0[t] / (float)NPTS;
        float v = q0[t] / (float)NPTS - m * m;
        float inv = 1.0f / sqrtf(fmaxf(v, 0.f) + EPSB);
        sc[t] = g0[t] * inv;
        sh[t] = b0[t] - m * g0[t] * inv;
    }
    __syncthreads();
    if (t < 64) {
        float acc = b1[t];
#pragma unroll
        for (int f = 0; f < 7; ++f) {
            W1p[f * 64 + t] = W1[f * 64 + t] * sc[f];
            acc += sh[f] * W1[f * 64 + t];
        }
        b1p[t] = acc;
    }
}

__global__ void prep_bn_kernel(const float* __restrict__ sum, const float* __restrict__ sq,
                               const float* __restrict__ g, const float* __restrict__ b,
                               float* __restrict__ sc, float* __restrict__ sh, int C)
{
    int c = blockIdx.x * blockDim.x + threadIdx.x;
    if (c < C) {
        float m = sum[c] / (float)NPTS;
        float v = sq[c] / (float)NPTS - m * m;
        float inv = 1.0f / sqrtf(fmaxf(v, 0.f) + EPSB);
        sc[c] = g[c] * inv;
        sh[c] = b[c] - m * g[c] * inv;
    }
}

// ---- standalone bn+relu elementwise pass (in place, bf16x8 per thread) ----
template<int C>
__global__ __launch_bounds__(256) void bn_apply_kernel(
    unsigned short* __restrict__ y, const float* __restrict__ sc, const float* __restrict__ sh)
{
    __shared__ float scl[C], shl[C];
    int t = threadIdx.x;
    for (int i = t; i < C; i += 256) { scl[i] = sc[i]; shl[i] = sh[i]; }
    __syncthreads();
    size_t i8 = ((size_t)blockIdx.x * 256 + t) * 8;   // grid sized exactly MPAD*C/2048
    int col = (int)(i8 & (size_t)(C - 1));
    uint4 v = *(const uint4*)(y + i8);
    v.x = bnrelu_pack(v.x, scl[col+0], shl[col+0], scl[col+1], shl[col+1]);
    v.y = bnrelu_pack(v.y, scl[col+2], shl[col+2], scl[col+3], shl[col+3]);
    v.z = bnrelu_pack(v.z, scl[col+4], shl[col+4], scl[col+5], shl[col+5]);
    v.w = bnrelu_pack(v.w, scl[col+6], shl[col+6], scl[col+7], shl[col+7]);
    *(uint4*)(y + i8) = v;
}

// ---- weight transpose+cast: Wt[n][k] = bf16(W[k][n]) ----
__global__ __launch_bounds__(256) void wtrans_kernel(const float* __restrict__ W,
                                                     unsigned short* __restrict__ Wt,
                                                     int K, int N)
{
    int i = blockIdx.x * 256 + threadIdx.x;
    if (i < K * N) {
        int k = i / N, n = i % N;
        Wt[(size_t)n * K + k] = f2bf(W[i]);
    }
}

// ---- layer 1: y1(bf16) = fea @ W1' + b1' (K=7, Nc=64) + fp32 col stats ----
__global__ __launch_bounds__(256) void layer1_kernel(
    const float* __restrict__ fea, const float* __restrict__ W1p, const float* __restrict__ b1p,
    unsigned short* __restrict__ y1, float* __restrict__ sum1, float* __restrict__ sq1)
{
    __shared__ float Wl[448], bl[64], feaL[448];
    __shared__ float red[4][64];
    int t = threadIdx.x;
    int p0 = blockIdx.x * 64;
    for (int i = t; i < 448; i += 256) { Wl[i] = W1p[i]; feaL[i] = fea[(size_t)p0 * 7 + i]; }
    if (t < 64) bl[t] = b1p[t];
    __syncthreads();
    int c = t & 63, pr = t >> 6;
    float s = 0.f, q = 0.f;
#pragma unroll
    for (int it = 0; it < 16; ++it) {
        int pl = it * 4 + pr;
        float v = bl[c];
#pragma unroll
        for (int f = 0; f < 7; ++f) v = fmaf(feaL[pl * 7 + f], Wl[f * 64 + c], v);
        y1[(size_t)(p0 + pl) * 64 + c] = f2bf(v);
        s += v; q += v * v;
    }
    red[pr][c] = s; __syncthreads();
    if (t < 64) atomicAdd(&sum1[c], red[0][c] + red[1][c] + red[2][c] + red[3][c]);
    __syncthreads();
    red[pr][c] = q; __syncthreads();
    if (t < 64) atomicAdd(&sq1[c], red[0][c] + red[1][c] + red[2][c] + red[3][c]);
}

// ---- MFMA GEMM v5: 128x64 tile, 2 waves/block (TLP over ILP) ----
// Y = A @ Wt^T + bias; BK=32 via global_load_lds width=16; LDS 12.3KB ->
// ~8 independent blocks/CU, so cross-block overlap hides the barrier drains.
template<int K, int NC, bool STATS>
__global__ __launch_bounds__(128, 4) void gemm_mfma_async(
    const unsigned short* __restrict__ A, const unsigned short* __restrict__ Wt,
    const float* __restrict__ bias, unsigned short* __restrict__ Y,
    float* __restrict__ osum, float* __restrict__ osq)
{
    __shared__ __align__(16) unsigned short lds[6144];  // As 8KB | Bs 4KB; C-half reuses
    unsigned short* As = lds;            // [128][32] contiguous (async-load order)
    unsigned short* Bs = lds + 4096;     // [64][32]
    __shared__ float bcols[64], colsum[64], colsq[64];
    int t = threadIdx.x;
    int m0 = blockIdx.x * 128, c0 = blockIdx.y * 64;
    if (t < 64) {
        bcols[t] = bias[c0 + t];
        if (STATS) { colsum[t] = 0.f; colsq[t] = 0.f; }
    }
    int lane = t & 63, w = t >> 6, quad = lane >> 4, lr = lane & 15;
    f32x4 acc[4][4];
#pragma unroll
    for (int i = 0; i < 4; ++i)
#pragma unroll
        for (int j = 0; j < 4; ++j) acc[i][j] = (f32x4){0.f, 0.f, 0.f, 0.f};

    for (int kt = 0; kt < K; kt += 32) {
        __syncthreads();
#pragma unroll
        for (int i = 0; i < 4; ++i) {        // A tile: 128 rows x 32 k (512 x 16B chunks)
            int c = t + i * 128;
            int row = c >> 2, off = (c & 3) * 8;
            async16(A + (size_t)(m0 + row) * K + kt + off, As + row * 32 + off);
        }
#pragma unroll
        for (int i = 0; i < 2; ++i) {        // B tile: 64 n x 32 k
            int c = t + i * 128;
            int n = c >> 2, off = (c & 3) * 8;
            async16(Wt + (size_t)(c0 + n) * K + kt + off, Bs + n * 32 + off);
        }
        __syncthreads();
        short8 af[4], bfr[4];
#pragma unroll
        for (int mi = 0; mi < 4; ++mi)
            af[mi] = *(const short8*)&As[(w * 64 + mi * 16 + lr) * 32 + quad * 8];
#pragma unroll
        for (int ni = 0; ni < 4; ++ni)
            bfr[ni] = *(const short8*)&Bs[(ni * 16 + lr) * 32 + quad * 8];
#pragma unroll
        for (int mi = 0; mi < 4; ++mi)
#pragma unroll
            for (int ni = 0; ni < 4; ++ni)
                acc[mi][ni] = __builtin_amdgcn_mfma_f32_16x16x32_bf16(
                    af[mi], bfr[ni], acc[mi][ni], 0, 0, 0);
    }
    __syncthreads();   // K-loop ds_reads done; reuse lds as half C-stage [64][72]
    // C/D layout: col=lane&15, row=quad*4+reg. Wave w owns rows w*64..+63.
#pragma unroll
    for (int half = 0; half < 2; ++half) {
        if (w == half) {
#pragma unroll
            for (int ni = 0; ni < 4; ++ni) {
                int col = ni * 16 + lr;
                float bv = bcols[col];
                float s = 0.f, q = 0.f;
#pragma unroll
                for (int mi = 0; mi < 4; ++mi) {
                    int rb = mi * 16 + quad * 4;           // local row within half
#pragma unroll
                    for (int r = 0; r < 4; ++r) {
                        float v = acc[mi][ni][r] + bv;
                        lds[(rb + r) * 72 + col] = f2bf(v);
                        if (STATS && (m0 + half * 64 + rb + r) < NPTS) { s += v; q += v * v; }
                    }
                }
                if (STATS) {
                    atomicAdd(&colsum[col], s);
                    atomicAdd(&colsq[col], q);
                }
            }
        }
        __syncthreads();
#pragma unroll
        for (int i = 0; i < 4; ++i) {      // 64x64 bf16 half-tile, full-line stores
            int idx = i * 128 + t;
            int row = idx >> 3, colq = (idx & 7) * 8;
            *(uint4*)(Y + (size_t)(m0 + half * 64 + row) * NC + c0 + colq) =
                *(const uint4*)&lds[row * 72 + colq];
        }
        if (half == 0) __syncthreads();    // stores read lds before half1 overwrites
    }
    if (STATS && t < 64) {
        atomicAdd(&osum[c0 + t], colsum[t]);
        atomicAdd(&osq[c0 + t], colsq[t]);
    }
}

// ---- sort machinery: histogram, 3-phase exclusive scan, index scatter ----
__global__ __launch_bounds__(256) void hist_kernel(const int* __restrict__ xy,
                                                   int* __restrict__ cnt)
{
    int p = blockIdx.x * 256 + threadIdx.x;
    if (p < NPTS) {
        int id = xy[(size_t)p * 2] * GYD + xy[(size_t)p * 2 + 1];
        atomicAdd(&cnt[id], 1);
    }
}

__global__ __launch_bounds__(256) void scanA_kernel(const int* __restrict__ cnt,
                                                    int* __restrict__ csum)
{
    __shared__ int red[256];
    int t = threadIdx.x, base = blockIdx.x * 2048;
    int s = 0;
    for (int i = t; i < 2048; i += 256) {
        int idx = base + i;
        if (idx < SEGR) s += cnt[idx];
    }
    red[t] = s; __syncthreads();
    for (int o = 128; o > 0; o >>= 1) { if (t < o) red[t] += red[t + o]; __syncthreads(); }
    if (t == 0) csum[blockIdx.x] = red[0];
}

__global__ void scanB_kernel(int* __restrict__ csum, int* __restrict__ offs)
{
    if (threadIdx.x == 0) {
        int run = 0;
        for (int i = 0; i < 64; ++i) { int v = csum[i]; csum[i] = run; run += v; }
        offs[SEGR] = run;
    }
}

__global__ __launch_bounds__(256) void scanC_kernel(const int* __restrict__ cnt,
                                                    const int* __restrict__ csum,
                                                    int* __restrict__ offs,
                                                    int* __restrict__ cursor)
{
    __shared__ int red[256];
    int t = threadIdx.x, base = blockIdx.x * 2048;
    int v[8]; int s = 0;
#pragma unroll
    for (int i = 0; i < 8; ++i) {
        int idx = base + t * 8 + i;
        v[i] = (idx < SEGR) ? cnt[idx] : 0;
        s += v[i];
    }
    red[t] = s; __syncthreads();
    for (int o = 1; o < 256; o <<= 1) {
        int x = (t >= o) ? red[t - o] : 0;
        __syncthreads();
        red[t] += x;
        __syncthreads();
    }
    int run = red[t] - s + csum[blockIdx.x];
#pragma unroll
    for (int i = 0; i < 8; ++i) {
        int idx = base + t * 8 + i;
        if (idx < SEGR) { offs[idx] = run; cursor[idx] = run; }
        run += v[i];
    }
}

__global__ __launch_bounds__(256) void scatter_idx_kernel(const int* __restrict__ xy,
                                                          int* __restrict__ cursor,
                                                          int* __restrict__ order)
{
    int p = blockIdx.x * 256 + threadIdx.x;
    if (p < NPTS) {
        int id = xy[(size_t)p * 2] * GYD + xy[(size_t)p * 2 + 1];
        int pos = atomicAdd(&cursor[id], 1);
        order[pos] = p;
    }
}

// ---- fused gather-segmax + partial L5: E[cell][32] (+)= max_pts(y4g) @ W5[g-slice] ----
__global__ __launch_bounds__(256) void segmax_l5_kernel(
    const unsigned short* __restrict__ y4g, const unsigned short* __restrict__ Wt5,
    const int* __restrict__ offs, const int* __restrict__ order,
    int g, float* __restrict__ E)
{
    __shared__ __align__(16) unsigned short seg[64 * 136];
    __shared__ __align__(16) unsigned short w5s[32 * 136];
    __shared__ int offs_s[65];
    int t = threadIdx.x;
    int c0 = blockIdx.x * 64;
    if (t < 65) offs_s[t] = offs[c0 + t];
    {   // stage Wt5[n=0..31][k = g*128 .. +128]
        int n = t >> 3, ko = (t & 7) * 16;
        *(uint4*)&w5s[n * 136 + ko]     = *(const uint4*)(Wt5 + (size_t)n * 512 + g * 128 + ko);
        *(uint4*)&w5s[n * 136 + ko + 8] = *(const uint4*)(Wt5 + (size_t)n * 512 + g * 128 + ko + 8);
    }
    __syncthreads();
    int cell = t >> 2, q = t & 3;
    float mx[32];
#pragma unroll
    for (int i = 0; i < 32; ++i) mx[i] = -3.0e38f;
    int jb = offs_s[cell], je = offs_s[cell + 1];
    for (int j = jb; j < je; ++j) {
        int p = order[j];
        const uint4* rp = (const uint4*)(y4g + (size_t)p * 128 + q * 32);
#pragma unroll
        for (int u = 0; u < 4; ++u) {
            uint4 vv = rp[u];
            unsigned int wv[4] = {vv.x, vv.y, vv.z, vv.w};
#pragma unroll
            for (int k2 = 0; k2 < 4; ++k2) {
                int idx = u * 8 + k2 * 2;
                mx[idx]     = fmaxf(mx[idx],     bf2f((unsigned short)(wv[k2] & 0xffffu)));
                mx[idx + 1] = fmaxf(mx[idx + 1], bf2f((unsigned short)(wv[k2] >> 16)));
            }
        }
    }
    bool empty = (jb == je);
#pragma unroll
    for (int i = 0; i < 16; ++i) {
        float lo = empty ? 0.f : mx[2 * i], hi = empty ? 0.f : mx[2 * i + 1];
        unsigned int pk = (unsigned int)f2bf(lo) | ((unsigned int)f2bf(hi) << 16);
        *(unsigned int*)&seg[cell * 136 + q * 32 + 2 * i] = pk;
    }
    __syncthreads();
    int lane = t & 63, w = t >> 6, quad = lane >> 4, lr = lane & 15;
    f32x4 acc[2];
    acc[0] = (f32x4){0.f, 0.f, 0.f, 0.f};
    acc[1] = (f32x4){0.f, 0.f, 0.f, 0.f};
#pragma unroll
    for (int kt = 0; kt < 4; ++kt) {
        short8 af = *(const short8*)&seg[(w * 16 + lr) * 136 + kt * 32 + quad * 8];
#pragma unroll
        for (int ni = 0; ni < 2; ++ni) {
            short8 bfr = *(const short8*)&w5s[(ni * 16 + lr) * 136 + kt * 32 + quad * 8];
            acc[ni] = __builtin_amdgcn_mfma_f32_16x16x32_bf16(af, bfr, acc[ni], 0, 0, 0);
        }
    }
#pragma unroll
    for (int ni = 0; ni < 2; ++ni) {
        int h = ni * 16 + lr;
#pragma unroll
        for (int r = 0; r < 4; ++r) {
            int cr = w * 16 + quad * 4 + r;
            float* ep = E + (size_t)(c0 + cr) * 32 + h;
            float v = acc[ni][r];
            if (g > 0) v += *ep;
            *ep = v;
        }
    }
}

// ---- output: out[h][cell] = occ ? relu(E[cell][h] + b5[h]) : 0 ----
__global__ __launch_bounds__(256) void out_kernel(
    const float* __restrict__ E, const int* __restrict__ cnt,
    const float* __restrict__ b5, float* __restrict__ out)
{
    int t = threadIdx.x;
    int c0 = blockIdx.x * 64;
    int lane = t & 63, hq = t >> 6;
    int cell = c0 + lane;
    if (c0 >= SEGR) {
#pragma unroll
        for (int j = 0; j < 8; ++j)
            out[(size_t)(hq * 8 + j) * NSEG + cell] = 0.f;
        return;
    }
    bool oc = cnt[cell] > 0;
    float4 e0 = *(const float4*)(E + (size_t)cell * 32 + hq * 8);
    float4 e1 = *(const float4*)(E + (size_t)cell * 32 + hq * 8 + 4);
    float r[8] = {e0.x, e0.y, e0.z, e0.w, e1.x, e1.y, e1.z, e1.w};
#pragma unroll
    for (int j = 0; j < 8; ++j) {
        float v = oc ? fmaxf(r[j] + b5[hq * 8 + j], 0.f) : 0.f;
        out[(size_t)(hq * 8 + j) * NSEG + cell] = v;
    }
}

extern "C" void kernel_launch(void* const* d_in, const int* in_sizes, int n_in,
                              void* d_out, int out_size, void* d_ws, size_t ws_size,
                              hipStream_t stream)
{
    const float* pt_fea = (const float*)d_in[0];
    const int*   xy_ind = (const int*)d_in[1];
    const float* bn0_g  = (const float*)d_in[2];
    const float* bn0_b  = (const float*)d_in[3];
    const float* W1     = (const float*)d_in[4];
    const float* b1     = (const float*)d_in[5];
    const float* bn1_g  = (const float*)d_in[6];
    const float* bn1_b  = (const float*)d_in[7];
    const float* W2     = (const float*)d_in[8];
    const float* b2     = (const float*)d_in[9];
    const float* bn2_g  = (const float*)d_in[10];
    const float* bn2_b  = (const float*)d_in[11];
    const float* W3     = (const float*)d_in[12];
    const float* b3     = (const float*)d_in[13];
    const float* bn3_g  = (const float*)d_in[14];
    const float* bn3_b  = (const float*)d_in[15];
    const float* W4     = (const float*)d_in[16];
    const float* b4     = (const float*)d_in[17];
    const float* W5     = (const float*)d_in[18];
    const float* b5     = (const float*)d_in[19];
    float* out = (float*)d_out;

    // ---- workspace layout (~111 MB, unchanged from R4..R7) ----
    const size_t oY2   = 61472768;                 // MPAD*256*2
    const size_t oE    = oY2 + (size_t)MPAD * 128 * 2;
    const size_t oCnt  = oE + (size_t)SEGR * 32 * 4;
    const size_t oOffs = oCnt + 518400;
    const size_t oCur  = oOffs + 518528;
    const size_t oOrd  = oCur + 518400;
    const size_t oCsum = oOrd + 480000;
    const size_t oSt   = oCsum + 512;
    const size_t oWt2  = oSt + 16384;
    const size_t oWt3  = oWt2 + 16384;
    const size_t oWt4  = oWt3 + 65536;
    const size_t oWt5  = oWt4 + 262144;

    unsigned short* y1   = (unsigned short*)d_ws;
    unsigned short* y3   = (unsigned short*)d_ws;
    unsigned short* y2   = (unsigned short*)((char*)d_ws + oY2);
    unsigned short* y4g  = (unsigned short*)((char*)d_ws + oY2);
    float*          E    = (float*)((char*)d_ws + oE);
    int*            cnt  = (int*)((char*)d_ws + oCnt);
    int*            offs = (int*)((char*)d_ws + oOffs);
    int*            cur  = (int*)((char*)d_ws + oCur);
    int*            ord  = (int*)((char*)d_ws + oOrd);
    int*            csum = (int*)((char*)d_ws + oCsum);
    float*          st   = (float*)((char*)d_ws + oSt);
    unsigned short* Wt2  = (unsigned short*)((char*)d_ws + oWt2);
    unsigned short* Wt3  = (unsigned short*)((char*)d_ws + oWt3);
    unsigned short* Wt4  = (unsigned short*)((char*)d_ws + oWt4);
    unsigned short* Wt5  = (unsigned short*)((char*)d_ws + oWt5);

    float* s0 = st + 0;     float* q0 = st + 8;
    float* W1p = st + 16;   float* b1p = st + 464;
    float* sum1 = st + 528; float* sq1 = st + 592; float* sc1 = st + 656; float* sh1 = st + 720;
    float* sum2 = st + 784; float* sq2 = st + 912; float* sc2 = st + 1040; float* sh2 = st + 1168;
    float* sum3 = st + 1296; float* sq3 = st + 1552; float* sc3 = st + 1808; float* sh3 = st + 2064;

    const int MB = MPAD / 128;   // 938

    wtrans_kernel<<<(64 * 128 + 255) / 256, 256, 0, stream>>>(W2, Wt2, 64, 128);
    wtrans_kernel<<<(128 * 256 + 255) / 256, 256, 0, stream>>>(W3, Wt3, 128, 256);
    wtrans_kernel<<<(256 * 512 + 255) / 256, 256, 0, stream>>>(W4, Wt4, 256, 512);
    wtrans_kernel<<<(512 * 32 + 255) / 256, 256, 0, stream>>>(W5, Wt5, 512, 32);

    for (int b = 0; b < 2; ++b) {
        const float* fea_b = pt_fea + (size_t)b * NPTS * 7;
        const int*   xy_b  = xy_ind + (size_t)b * NPTS * 2;
        float*       out_b = out + (size_t)b * NHD * NSEG;

        (void)hipMemsetAsync(st, 0, 2320 * sizeof(float), stream);
        (void)hipMemsetAsync(cnt, 0, (size_t)SEGR * 4, stream);

        bn0_stats_kernel<<<128, 256, 0, stream>>>(fea_b, s0, q0);
        prep0_kernel<<<1, 64, 0, stream>>>(s0, q0, bn0_g, bn0_b, W1, b1, W1p, b1p);
        layer1_kernel<<<NPTS / 64, 256, 0, stream>>>(fea_b, W1p, b1p, y1, sum1, sq1);
        prep_bn_kernel<<<1, 64, 0, stream>>>(sum1, sq1, bn1_g, bn1_b, sc1, sh1, 64);
        bn_apply_kernel<64><<<MPAD / 32, 256, 0, stream>>>(y1, sc1, sh1);
        gemm_mfma_async<64, 128, true><<<dim3(MB, 2), 128, 0, stream>>>(
            y1, Wt2, b2, y2, sum2, sq2);
        prep_bn_kernel<<<1, 128, 0, stream>>>(sum2, sq2, bn2_g, bn2_b, sc2, sh2, 128);
        bn_apply_kernel<128><<<MPAD / 16, 256, 0, stream>>>(y2, sc2, sh2);
        gemm_mfma_async<128, 256, true><<<dim3(MB, 4), 128, 0, stream>>>(
            y2, Wt3, b3, y3, sum3, sq3);
        prep_bn_kernel<<<1, 256, 0, stream>>>(sum3, sq3, bn3_g, bn3_b, sc3, sh3, 256);
        bn_apply_kernel<256><<<MPAD / 8, 256, 0, stream>>>(y3, sc3, sh3);

        hist_kernel<<<(NPTS + 255) / 256, 256, 0, stream>>>(xy_b, cnt);
        scanA_kernel<<<64, 256, 0, stream>>>(cnt, csum);
        scanB_kernel<<<1, 64, 0, stream>>>(csum, offs);
        scanC_kernel<<<64, 256, 0, stream>>>(cnt, csum, offs, cur);
        scatter_idx_kernel<<<(NPTS + 255) / 256, 256, 0, stream>>>(xy_b, cur, ord);

        for (int g = 0; g < 4; ++g) {
            gemm_mfma_async<256, 128, false><<<dim3(MB, 2), 128, 0, stream>>>(
                y3, Wt4 + (size_t)g * 128 * 256, b4 + g * 128, y4g, nullptr, nullptr);
            segmax_l5_kernel<<<SEGR / 64, 256, 0, stream>>>(y4g, Wt5, offs, ord, g, E);
        }
        out_kernel<<<NSEG / 64, 256, 0, stream>>>(E, cnt, b5, out_b);
    }
}

// Round 9
// 979.999 us; speedup vs baseline: 1.0635x; 1.0635x over previous
//
#include <hip/hip_runtime.h>
#include <cstdint>

#define GXD 480
#define GYD 360
#define NHD 32
#define NPTS 120000
#define MPAD 120064           // NPTS padded to multiple of 256
#define SEGR 129600           // 360*360 possible ids
#define NSEG (GXD*GYD)        // 172800
#define EPSB 1e-5f

using short8 = __attribute__((ext_vector_type(8))) short;   // 8 bf16 in 4 VGPRs
using f32x4  = __attribute__((ext_vector_type(4))) float;   // MFMA accumulator

// ---- bf16 helpers ----
__device__ __forceinline__ float bf2f(unsigned short u) {
    return __uint_as_float(((unsigned int)u) << 16);
}
__device__ __forceinline__ unsigned short f2bf(float f) {
    unsigned int u = __float_as_uint(f);
    u += 0x7fffu + ((u >> 16) & 1u);   // round-to-nearest-even
    return (unsigned short)(u >> 16);
}
__device__ __forceinline__ unsigned int bnrelu_pack(unsigned int wv, float sc0, float sh0,
                                                    float sc1, float sh1)
{
    float lo = fmaxf(fmaf(bf2f((unsigned short)(wv & 0xffffu)), sc0, sh0), 0.f);
    float hi = fmaxf(fmaf(bf2f((unsigned short)(wv >> 16)), sc1, sh1), 0.f);
    return (unsigned int)f2bf(lo) | ((unsigned int)f2bf(hi) << 16);
}

// ---- async global->LDS, 16B per lane (dest = wave-uniform base + lane*16) ----
__device__ __forceinline__ void async16(const unsigned short* g, unsigned short* l)
{
    __builtin_amdgcn_global_load_lds(
        (const __attribute__((address_space(1))) unsigned int*)g,
        (__attribute__((address_space(3))) unsigned int*)l, 16, 0, 0);
}

// ---- bn0 stats ----
__global__ __launch_bounds__(256) void bn0_stats_kernel(
    const float* __restrict__ fea, float* __restrict__ s0, float* __restrict__ q0)
{
    float s[7] = {0,0,0,0,0,0,0}, q[7] = {0,0,0,0,0,0,0};
    for (int p = blockIdx.x * 256 + threadIdx.x; p < NPTS; p += gridDim.x * 256) {
        const float* r = fea + (size_t)p * 7;
#pragma unroll
        for (int f = 0; f < 7; ++f) { float v = r[f]; s[f] += v; q[f] += v * v; }
    }
    __shared__ float red[256];
    int t = threadIdx.x;
#pragma unroll
    for (int f = 0; f < 7; ++f) {
        red[t] = s[f]; __syncthreads();
        for (int o = 128; o > 0; o >>= 1) {
            if (t < o) red[t] += red[t + o];
            __syncthreads();
        }
        if (t == 0) atomicAdd(&s0[f], red[0]);
        __syncthreads();
        red[t] = q[f]; __syncthreads();
        for (int o = 128; o > 0; o >>= 1) {
            if (t < o) red[t] += red[t + o];
            __syncthreads();
        }
        if (t == 0) atomicAdd(&q0[f], red[0]);
        __syncthreads();
    }
}

// ---- fold bn0 into W1 ----
__global__ void prep0_kernel(const float* __restrict__ s0, const float* __restrict__ q0,
                             const float* __restrict__ g0, const float* __restrict__ b0,
                             const float* __restrict__ W1, const float* __restrict__ b1,
                             float* __restrict__ W1p, float* __restrict__ b1p)
{
    __shared__ float sc[7], sh[7];
    int t = threadIdx.x;
    if (t < 7) {
        float m = s0[t] / (float)NPTS;
        float v = q0[t] / (float)NPTS - m * m;
        float inv = 1.0f / sqrtf(fmaxf(v, 0.f) + EPSB);
        sc[t] = g0[t] * inv;
        sh[t] = b0[t] - m * g0[t] * inv;
    }
    __syncthreads();
    if (t < 64) {
        float acc = b1[t];
#pragma unroll
        for (int f = 0; f < 7; ++f) {
            W1p[f * 64 + t] = W1[f * 64 + t] * sc[f];
            acc += sh[f] * W1[f * 64 + t];
        }
        b1p[t] = acc;
    }
}

__global__ void prep_bn_kernel(const float* __restrict__ sum, const float* __restrict__ sq,
                               const float* __restrict__ g, const float* __restrict__ b,
                               float* __restrict__ sc, float* __restrict__ sh, int C)
{
    int c = blockIdx.x * blockDim.x + threadIdx.x;
    if (c < C) {
        float m = sum[c] / (float)NPTS;
        float v = sq[c] / (float)NPTS - m * m;
        float inv = 1.0f / sqrtf(fmaxf(v, 0.f) + EPSB);
        sc[c] = g[c] * inv;
        sh[c] = b[c] - m * g[c] * inv;
    }
}

// ---- standalone bn+relu elementwise pass (in place, bf16x8 per thread) ----
template<int C>
__global__ __launch_bounds__(256) void bn_apply_kernel(
    unsigned short* __restrict__ y, const float* __restrict__ sc, const float* __restrict__ sh)
{
    __shared__ float scl[C], shl[C];
    int t = threadIdx.x;
    for (int i = t; i < C; i += 256) { scl[i] = sc[i]; shl[i] = sh[i]; }
    __syncthreads();
    size_t i8 = ((size_t)blockIdx.x * 256 + t) * 8;   // grid sized exactly MPAD*C/2048
    int col = (int)(i8 & (size_t)(C - 1));
    uint4 v = *(const uint4*)(y + i8);
    v.x = bnrelu_pack(v.x, scl[col+0], shl[col+0], scl[col+1], shl[col+1]);
    v.y = bnrelu_pack(v.y, scl[col+2], shl[col+2], scl[col+3], shl[col+3]);
    v.z = bnrelu_pack(v.z, scl[col+4], shl[col+4], scl[col+5], shl[col+5]);
    v.w = bnrelu_pack(v.w, scl[col+6], shl[col+6], scl[col+7], shl[col+7]);
    *(uint4*)(y + i8) = v;
}

// ---- weight transpose+cast: Wt[n][k] = bf16(W[k][n]) ----
__global__ __launch_bounds__(256) void wtrans_kernel(const float* __restrict__ W,
                                                     unsigned short* __restrict__ Wt,
                                                     int K, int N)
{
    int i = blockIdx.x * 256 + threadIdx.x;
    if (i < K * N) {
        int k = i / N, n = i % N;
        Wt[(size_t)n * K + k] = f2bf(W[i]);
    }
}

// ---- layer 1: y1(bf16) = fea @ W1' + b1' (K=7, Nc=64) + fp32 col stats ----
__global__ __launch_bounds__(256) void layer1_kernel(
    const float* __restrict__ fea, const float* __restrict__ W1p, const float* __restrict__ b1p,
    unsigned short* __restrict__ y1, float* __restrict__ sum1, float* __restrict__ sq1)
{
    __shared__ float Wl[448], bl[64], feaL[448];
    __shared__ float red[4][64];
    int t = threadIdx.x;
    int p0 = blockIdx.x * 64;
    for (int i = t; i < 448; i += 256) { Wl[i] = W1p[i]; feaL[i] = fea[(size_t)p0 * 7 + i]; }
    if (t < 64) bl[t] = b1p[t];
    __syncthreads();
    int c = t & 63, pr = t >> 6;
    float s = 0.f, q = 0.f;
#pragma unroll
    for (int it = 0; it < 16; ++it) {
        int pl = it * 4 + pr;
        float v = bl[c];
#pragma unroll
        for (int f = 0; f < 7; ++f) v = fmaf(feaL[pl * 7 + f], Wl[f * 64 + c], v);
        y1[(size_t)(p0 + pl) * 64 + c] = f2bf(v);
        s += v; q += v * v;
    }
    red[pr][c] = s; __syncthreads();
    if (t < 64) atomicAdd(&sum1[c], red[0][c] + red[1][c] + red[2][c] + red[3][c]);
    __syncthreads();
    red[pr][c] = q; __syncthreads();
    if (t < 64) atomicAdd(&sq1[c], red[0][c] + red[1][c] + red[2][c] + red[3][c]);
}

// ---- MFMA GEMM v6: WAVE-PRIVATE staging, no barriers in the K-loop ----
// Block = 4 waves; wave w computes rows [m0 + w*64, +64) x cols [c0, c0+64) with
// its own 8KB LDS slab. Sync = s_waitcnt vmcnt(0) only; waves drift freely.
template<int K, int NC, bool STATS>
__global__ __launch_bounds__(256) void gemm_wave(
    const unsigned short* __restrict__ A, const unsigned short* __restrict__ Wt,
    const float* __restrict__ bias, unsigned short* __restrict__ Y,
    float* __restrict__ osum, float* __restrict__ osq)
{
    __shared__ __align__(16) unsigned short lds[4 * 4096];  // 8KB per wave
    __shared__ float colsum[64], colsq[64];
    int t = threadIdx.x;
    int w = t >> 6, ln = t & 63, quad = ln >> 4, lr = ln & 15;
    int mb = blockIdx.x * 256 + w * 64;
    int c0 = blockIdx.y * 64;
    unsigned short* Aw = lds + w * 4096;        // [64][32] ushort, 4KB
    unsigned short* Bw = Aw + 2048;             // [64][32] ushort, 4KB

    if (STATS) {
        if (t < 64) { colsum[t] = 0.f; colsq[t] = 0.f; }
        __syncthreads();                         // once, before K-loop
    }

    const int grow4 = ln >> 2, koff = (ln & 3) * 8;   // 4 lanes per row, 8 bf16 each
    f32x4 acc[4][4];
#pragma unroll
    for (int i = 0; i < 4; ++i)
#pragma unroll
        for (int j = 0; j < 4; ++j) acc[i][j] = (f32x4){0.f, 0.f, 0.f, 0.f};

    for (int kt = 0; kt < K; kt += 32) {
#pragma unroll
        for (int i = 0; i < 4; ++i) {            // A: 64 rows x 32 k, wave-private
            async16(A + (size_t)(mb + i * 16 + grow4) * K + kt + koff,
                    Aw + i * 512 + ln * 8);
            async16(Wt + (size_t)(c0 + i * 16 + grow4) * K + kt + koff,
                    Bw + i * 512 + ln * 8);
        }
        asm volatile("s_waitcnt vmcnt(0)" ::: "memory");
        short8 af[4], bfr[4];
#pragma unroll
        for (int mi = 0; mi < 4; ++mi)
            af[mi] = *(const short8*)&Aw[(mi * 16 + lr) * 32 + quad * 8];
#pragma unroll
        for (int ni = 0; ni < 4; ++ni)
            bfr[ni] = *(const short8*)&Bw[(ni * 16 + lr) * 32 + quad * 8];
        asm volatile("s_waitcnt lgkmcnt(0)" ::: "memory");  // frags read before re-stage
#pragma unroll
        for (int mi = 0; mi < 4; ++mi)
#pragma unroll
            for (int ni = 0; ni < 4; ++ni)
                acc[mi][ni] = __builtin_amdgcn_mfma_f32_16x16x32_bf16(
                    af[mi], bfr[ni], acc[mi][ni], 0, 0, 0);
    }

    // wave-private epilogue: C-stage 64x64 bf16 in own slab (A+B dead), no barriers
    unsigned short* Cw = Aw;                     // 8KB = 64*64 ushort exactly
    // C/D layout: col=lane&15, row=quad*4+reg
#pragma unroll
    for (int ni = 0; ni < 4; ++ni) {
        int col = ni * 16 + lr;
        float bv = bias[c0 + col];
        float s = 0.f, q = 0.f;
#pragma unroll
        for (int mi = 0; mi < 4; ++mi) {
            int rb = mi * 16 + quad * 4;
#pragma unroll
            for (int r = 0; r < 4; ++r) {
                float v = acc[mi][ni][r] + bv;
                Cw[(rb + r) * 64 + col] = f2bf(v);
                if (STATS && (mb + rb + r) < NPTS) { s += v; q += v * v; }
            }
        }
        if (STATS) {
            atomicAdd(&colsum[col], s);          // LDS atomics, no barrier needed
            atomicAdd(&colsq[col], q);
        }
    }
#pragma unroll
    for (int i = 0; i < 8; ++i) {                // 64x64 tile, full-line uint4 stores
        int idx = i * 64 + ln;
        int row = idx >> 3, colq = (idx & 7) * 8;
        *(uint4*)(Y + (size_t)(mb + row) * NC + c0 + colq) = *(const uint4*)&Cw[row * 64 + colq];
    }
    if (STATS) {
        __syncthreads();                         // once, after all waves' LDS atomics
        if (t < 64) {
            atomicAdd(&osum[c0 + t], colsum[t]);
            atomicAdd(&osq[c0 + t], colsq[t]);
        }
    }
}

// ---- sort machinery: histogram, 3-phase exclusive scan, index scatter ----
__global__ __launch_bounds__(256) void hist_kernel(const int* __restrict__ xy,
                                                   int* __restrict__ cnt)
{
    int p = blockIdx.x * 256 + threadIdx.x;
    if (p < NPTS) {
        int id = xy[(size_t)p * 2] * GYD + xy[(size_t)p * 2 + 1];
        atomicAdd(&cnt[id], 1);
    }
}

__global__ __launch_bounds__(256) void scanA_kernel(const int* __restrict__ cnt,
                                                    int* __restrict__ csum)
{
    __shared__ int red[256];
    int t = threadIdx.x, base = blockIdx.x * 2048;
    int s = 0;
    for (int i = t; i < 2048; i += 256) {
        int idx = base + i;
        if (idx < SEGR) s += cnt[idx];
    }
    red[t] = s; __syncthreads();
    for (int o = 128; o > 0; o >>= 1) { if (t < o) red[t] += red[t + o]; __syncthreads(); }
    if (t == 0) csum[blockIdx.x] = red[0];
}

__global__ void scanB_kernel(int* __restrict__ csum, int* __restrict__ offs)
{
    if (threadIdx.x == 0) {
        int run = 0;
        for (int i = 0; i < 64; ++i) { int v = csum[i]; csum[i] = run; run += v; }
        offs[SEGR] = run;
    }
}

__global__ __launch_bounds__(256) void scanC_kernel(const int* __restrict__ cnt,
                                                    const int* __restrict__ csum,
                                                    int* __restrict__ offs,
                                                    int* __restrict__ cursor)
{
    __shared__ int red[256];
    int t = threadIdx.x, base = blockIdx.x * 2048;
    int v[8]; int s = 0;
#pragma unroll
    for (int i = 0; i < 8; ++i) {
        int idx = base + t * 8 + i;
        v[i] = (idx < SEGR) ? cnt[idx] : 0;
        s += v[i];
    }
    red[t] = s; __syncthreads();
    for (int o = 1; o < 256; o <<= 1) {
        int x = (t >= o) ? red[t - o] : 0;
        __syncthreads();
        red[t] += x;
        __syncthreads();
    }
    int run = red[t] - s + csum[blockIdx.x];
#pragma unroll
    for (int i = 0; i < 8; ++i) {
        int idx = base + t * 8 + i;
        if (idx < SEGR) { offs[idx] = run; cursor[idx] = run; }
        run += v[i];
    }
}

__global__ __launch_bounds__(256) void scatter_idx_kernel(const int* __restrict__ xy,
                                                          int* __restrict__ cursor,
                                                          int* __restrict__ order)
{
    int p = blockIdx.x * 256 + threadIdx.x;
    if (p < NPTS) {
        int id = xy[(size_t)p * 2] * GYD + xy[(size_t)p * 2 + 1];
        int pos = atomicAdd(&cursor[id], 1);
        order[pos] = p;
    }
}

// ---- fused gather-segmax + partial L5: E[cell][32] (+)= max_pts(y4g) @ W5[g-slice] ----
__global__ __launch_bounds__(256) void segmax_l5_kernel(
    const unsigned short* __restrict__ y4g, const unsigned short* __restrict__ Wt5,
    const int* __restrict__ offs, const int* __restrict__ order,
    int g, float* __restrict__ E)
{
    __shared__ __align__(16) unsigned short seg[64 * 136];
    __shared__ __align__(16) unsigned short w5s[32 * 136];
    __shared__ int offs_s[65];
    int t = threadIdx.x;
    int c0 = blockIdx.x * 64;
    if (t < 65) offs_s[t] = offs[c0 + t];
    {   // stage Wt5[n=0..31][k = g*128 .. +128]
        int n = t >> 3, ko = (t & 7) * 16;
        *(uint4*)&w5s[n * 136 + ko]     = *(const uint4*)(Wt5 + (size_t)n * 512 + g * 128 + ko);
        *(uint4*)&w5s[n * 136 + ko + 8] = *(const uint4*)(Wt5 + (size_t)n * 512 + g * 128 + ko + 8);
    }
    __syncthreads();
    int cell = t >> 2, q = t & 3;
    float mx[32];
#pragma unroll
    for (int i = 0; i < 32; ++i) mx[i] = -3.0e38f;
    int jb = offs_s[cell], je = offs_s[cell + 1];
    for (int j = jb; j < je; ++j) {
        int p = order[j];
        const uint4* rp = (const uint4*)(y4g + (size_t)p * 128 + q * 32);
#pragma unroll
        for (int u = 0; u < 4; ++u) {
            uint4 vv = rp[u];
            unsigned int wv[4] = {vv.x, vv.y, vv.z, vv.w};
#pragma unroll
            for (int k2 = 0; k2 < 4; ++k2) {
                int idx = u * 8 + k2 * 2;
                mx[idx]     = fmaxf(mx[idx],     bf2f((unsigned short)(wv[k2] & 0xffffu)));
                mx[idx + 1] = fmaxf(mx[idx + 1], bf2f((unsigned short)(wv[k2] >> 16)));
            }
        }
    }
    bool empty = (jb == je);
#pragma unroll
    for (int i = 0; i < 16; ++i) {
        float lo = empty ? 0.f : mx[2 * i], hi = empty ? 0.f : mx[2 * i + 1];
        unsigned int pk = (unsigned int)f2bf(lo) | ((unsigned int)f2bf(hi) << 16);
        *(unsigned int*)&seg[cell * 136 + q * 32 + 2 * i] = pk;
    }
    __syncthreads();
    int lane = t & 63, w = t >> 6, quad = lane >> 4, lr = lane & 15;
    f32x4 acc[2];
    acc[0] = (f32x4){0.f, 0.f, 0.f, 0.f};
    acc[1] = (f32x4){0.f, 0.f, 0.f, 0.f};
#pragma unroll
    for (int kt = 0; kt < 4; ++kt) {
        short8 af = *(const short8*)&seg[(w * 16 + lr) * 136 + kt * 32 + quad * 8];
#pragma unroll
        for (int ni = 0; ni < 2; ++ni) {
            short8 bfr = *(const short8*)&w5s[(ni * 16 + lr) * 136 + kt * 32 + quad * 8];
            acc[ni] = __builtin_amdgcn_mfma_f32_16x16x32_bf16(af, bfr, acc[ni], 0, 0, 0);
        }
    }
#pragma unroll
    for (int ni = 0; ni < 2; ++ni) {
        int h = ni * 16 + lr;
#pragma unroll
        for (int r = 0; r < 4; ++r) {
            int cr = w * 16 + quad * 4 + r;
            float* ep = E + (size_t)(c0 + cr) * 32 + h;
            float v = acc[ni][r];
            if (g > 0) v += *ep;
            *ep = v;
        }
    }
}

// ---- output: out[h][cell] = occ ? relu(E[cell][h] + b5[h]) : 0 ----
__global__ __launch_bounds__(256) void out_kernel(
    const float* __restrict__ E, const int* __restrict__ cnt,
    const float* __restrict__ b5, float* __restrict__ out)
{
    int t = threadIdx.x;
    int c0 = blockIdx.x * 64;
    int lane = t & 63, hq = t >> 6;
    int cell = c0 + lane;
    if (c0 >= SEGR) {
#pragma unroll
        for (int j = 0; j < 8; ++j)
            out[(size_t)(hq * 8 + j) * NSEG + cell] = 0.f;
        return;
    }
    bool oc = cnt[cell] > 0;
    float4 e0 = *(const float4*)(E + (size_t)cell * 32 + hq * 8);
    float4 e1 = *(const float4*)(E + (size_t)cell * 32 + hq * 8 + 4);
    float r[8] = {e0.x, e0.y, e0.z, e0.w, e1.x, e1.y, e1.z, e1.w};
#pragma unroll
    for (int j = 0; j < 8; ++j) {
        float v = oc ? fmaxf(r[j] + b5[hq * 8 + j], 0.f) : 0.f;
        out[(size_t)(hq * 8 + j) * NSEG + cell] = v;
    }
}

extern "C" void kernel_launch(void* const* d_in, const int* in_sizes, int n_in,
                              void* d_out, int out_size, void* d_ws, size_t ws_size,
                              hipStream_t stream)
{
    const float* pt_fea = (const float*)d_in[0];
    const int*   xy_ind = (const int*)d_in[1];
    const float* bn0_g  = (const float*)d_in[2];
    const float* bn0_b  = (const float*)d_in[3];
    const float* W1     = (const float*)d_in[4];
    const float* b1     = (const float*)d_in[5];
    const float* bn1_g  = (const float*)d_in[6];
    const float* bn1_b  = (const float*)d_in[7];
    const float* W2     = (const float*)d_in[8];
    const float* b2     = (const float*)d_in[9];
    const float* bn2_g  = (const float*)d_in[10];
    const float* bn2_b  = (const float*)d_in[11];
    const float* W3     = (const float*)d_in[12];
    const float* b3     = (const float*)d_in[13];
    const float* bn3_g  = (const float*)d_in[14];
    const float* bn3_b  = (const float*)d_in[15];
    const float* W4     = (const float*)d_in[16];
    const float* b4     = (const float*)d_in[17];
    const float* W5     = (const float*)d_in[18];
    const float* b5     = (const float*)d_in[19];
    float* out = (float*)d_out;

    // ---- workspace layout (~111 MB, unchanged from R4..R8) ----
    const size_t oY2   = 61472768;                 // MPAD*256*2
    const size_t oE    = oY2 + (size_t)MPAD * 128 * 2;
    const size_t oCnt  = oE + (size_t)SEGR * 32 * 4;
    const size_t oOffs = oCnt + 518400;
    const size_t oCur  = oOffs + 518528;
    const size_t oOrd  = oCur + 518400;
    const size_t oCsum = oOrd + 480000;
    const size_t oSt   = oCsum + 512;
    const size_t oWt2  = oSt + 16384;
    const size_t oWt3  = oWt2 + 16384;
    const size_t oWt4  = oWt3 + 65536;
    const size_t oWt5  = oWt4 + 262144;

    unsigned short* y1   = (unsigned short*)d_ws;
    unsigned short* y3   = (unsigned short*)d_ws;
    unsigned short* y2   = (unsigned short*)((char*)d_ws + oY2);
    unsigned short* y4g  = (unsigned short*)((char*)d_ws + oY2);
    float*          E    = (float*)((char*)d_ws + oE);
    int*            cnt  = (int*)((char*)d_ws + oCnt);
    int*            offs = (int*)((char*)d_ws + oOffs);
    int*            cur  = (int*)((char*)d_ws + oCur);
    int*            ord  = (int*)((char*)d_ws + oOrd);
    int*            csum = (int*)((char*)d_ws + oCsum);
    float*          st   = (float*)((char*)d_ws + oSt);
    unsigned short* Wt2  = (unsigned short*)((char*)d_ws + oWt2);
    unsigned short* Wt3  = (unsigned short*)((char*)d_ws + oWt3);
    unsigned short* Wt4  = (unsigned short*)((char*)d_ws + oWt4);
    unsigned short* Wt5  = (unsigned short*)((char*)d_ws + oWt5);

    float* s0 = st + 0;     float* q0 = st + 8;
    float* W1p = st + 16;   float* b1p = st + 464;
    float* sum1 = st + 528; float* sq1 = st + 592; float* sc1 = st + 656; float* sh1 = st + 720;
    float* sum2 = st + 784; float* sq2 = st + 912; float* sc2 = st + 1040; float* sh2 = st + 1168;
    float* sum3 = st + 1296; float* sq3 = st + 1552; float* sc3 = st + 1808; float* sh3 = st + 2064;

    const int MB256 = MPAD / 256;   // 469

    wtrans_kernel<<<(64 * 128 + 255) / 256, 256, 0, stream>>>(W2, Wt2, 64, 128);
    wtrans_kernel<<<(128 * 256 + 255) / 256, 256, 0, stream>>>(W3, Wt3, 128, 256);
    wtrans_kernel<<<(256 * 512 + 255) / 256, 256, 0, stream>>>(W4, Wt4, 256, 512);
    wtrans_kernel<<<(512 * 32 + 255) / 256, 256, 0, stream>>>(W5, Wt5, 512, 32);

    for (int b = 0; b < 2; ++b) {
        const float* fea_b = pt_fea + (size_t)b * NPTS * 7;
        const int*   xy_b  = xy_ind + (size_t)b * NPTS * 2;
        float*       out_b = out + (size_t)b * NHD * NSEG;

        (void)hipMemsetAsync(st, 0, 2320 * sizeof(float), stream);
        (void)hipMemsetAsync(cnt, 0, (size_t)SEGR * 4, stream);

        bn0_stats_kernel<<<128, 256, 0, stream>>>(fea_b, s0, q0);
        prep0_kernel<<<1, 64, 0, stream>>>(s0, q0, bn0_g, bn0_b, W1, b1, W1p, b1p);
        layer1_kernel<<<NPTS / 64, 256, 0, stream>>>(fea_b, W1p, b1p, y1, sum1, sq1);
        prep_bn_kernel<<<1, 64, 0, stream>>>(sum1, sq1, bn1_g, bn1_b, sc1, sh1, 64);
        bn_apply_kernel<64><<<MPAD / 32, 256, 0, stream>>>(y1, sc1, sh1);
        gemm_wave<64, 128, true><<<dim3(MB256, 2), 256, 0, stream>>>(
            y1, Wt2, b2, y2, sum2, sq2);
        prep_bn_kernel<<<1, 128, 0, stream>>>(sum2, sq2, bn2_g, bn2_b, sc2, sh2, 128);
        bn_apply_kernel<128><<<MPAD / 16, 256, 0, stream>>>(y2, sc2, sh2);
        gemm_wave<128, 256, true><<<dim3(MB256, 4), 256, 0, stream>>>(
            y2, Wt3, b3, y3, sum3, sq3);
        prep_bn_kernel<<<1, 256, 0, stream>>>(sum3, sq3, bn3_g, bn3_b, sc3, sh3, 256);
        bn_apply_kernel<256><<<MPAD / 8, 256, 0, stream>>>(y3, sc3, sh3);

        hist_kernel<<<(NPTS + 255) / 256, 256, 0, stream>>>(xy_b, cnt);
        scanA_kernel<<<64, 256, 0, stream>>>(cnt, csum);
        scanB_kernel<<<1, 64, 0, stream>>>(csum, offs);
        scanC_kernel<<<64, 256, 0, stream>>>(cnt, csum, offs, cur);
        scatter_idx_kernel<<<(NPTS + 255) / 256, 256, 0, stream>>>(xy_b, cur, ord);

        for (int g = 0; g < 4; ++g) {
            gemm_wave<256, 128, false><<<dim3(MB256, 2), 256, 0, stream>>>(
                y3, Wt4 + (size_t)g * 128 * 256, b4 + g * 128, y4g, nullptr, nullptr);
            segmax_l5_kernel<<<SEGR / 64, 256, 0, stream>>>(y4g, Wt5, offs, ord, g, E);
        }
        out_kernel<<<NSEG / 64, 256, 0, stream>>>(E, cnt, b5, out_b);
    }
}

// Round 10
// 929.506 us; speedup vs baseline: 1.1213x; 1.0543x over previous
//
#include <hip/hip_runtime.h>
#include <cstdint>

#define GXD 480
#define GYD 360
#define NHD 32
#define NPTS 120000
#define MPAD 120064           // NPTS padded to multiple of 128 (938*128)
#define SEGR 129600           // 360*360 possible ids
#define NSEG (GXD*GYD)        // 172800
#define EPSB 1e-5f

using short8 = __attribute__((ext_vector_type(8))) short;   // 8 bf16 in 4 VGPRs
using f32x4  = __attribute__((ext_vector_type(4))) float;   // MFMA accumulator

// ---- bf16 helpers ----
__device__ __forceinline__ float bf2f(unsigned short u) {
    return __uint_as_float(((unsigned int)u) << 16);
}
__device__ __forceinline__ unsigned short f2bf(float f) {
    unsigned int u = __float_as_uint(f);
    u += 0x7fffu + ((u >> 16) & 1u);   // round-to-nearest-even
    return (unsigned short)(u >> 16);
}
__device__ __forceinline__ unsigned int bnrelu_pack(unsigned int wv, float sc0, float sh0,
                                                    float sc1, float sh1)
{
    float lo = fmaxf(fmaf(bf2f((unsigned short)(wv & 0xffffu)), sc0, sh0), 0.f);
    float hi = fmaxf(fmaf(bf2f((unsigned short)(wv >> 16)), sc1, sh1), 0.f);
    return (unsigned int)f2bf(lo) | ((unsigned int)f2bf(hi) << 16);
}

// ---- async global->LDS, 16B per lane (dest = wave-uniform base + lane*16) ----
__device__ __forceinline__ void async16(const unsigned short* g, unsigned short* l)
{
    __builtin_amdgcn_global_load_lds(
        (const __attribute__((address_space(1))) unsigned int*)g,
        (__attribute__((address_space(3))) unsigned int*)l, 16, 0, 0);
}

// ---- bn0 stats ----
__global__ __launch_bounds__(256) void bn0_stats_kernel(
    const float* __restrict__ fea, float* __restrict__ s0, float* __restrict__ q0)
{
    float s[7] = {0,0,0,0,0,0,0}, q[7] = {0,0,0,0,0,0,0};
    for (int p = blockIdx.x * 256 + threadIdx.x; p < NPTS; p += gridDim.x * 256) {
        const float* r = fea + (size_t)p * 7;
#pragma unroll
        for (int f = 0; f < 7; ++f) { float v = r[f]; s[f] += v; q[f] += v * v; }
    }
    __shared__ float red[256];
    int t = threadIdx.x;
#pragma unroll
    for (int f = 0; f < 7; ++f) {
        red[t] = s[f]; __syncthreads();
        for (int o = 128; o > 0; o >>= 1) {
            if (t < o) red[t] += red[t + o];
            __syncthreads();
        }
        if (t == 0) atomicAdd(&s0[f], red[0]);
        __syncthreads();
        red[t] = q[f]; __syncthreads();
        for (int o = 128; o > 0; o >>= 1) {
            if (t < o) red[t] += red[t + o];
            __syncthreads();
        }
        if (t == 0) atomicAdd(&q0[f], red[0]);
        __syncthreads();
    }
}

// ---- fold bn0 into W1 ----
__global__ void prep0_kernel(const float* __restrict__ s0, const float* __restrict__ q0,
                             const float* __restrict__ g0, const float* __restrict__ b0,
                             const float* __restrict__ W1, const float* __restrict__ b1,
                             float* __restrict__ W1p, float* __restrict__ b1p)
{
    __shared__ float sc[7], sh[7];
    int t = threadIdx.x;
    if (t < 7) {
        float m = s0[t] / (float)NPTS;
        float v = q0[t] / (float)NPTS - m * m;
        float inv = 1.0f / sqrtf(fmaxf(v, 0.f) + EPSB);
        sc[t] = g0[t] * inv;
        sh[t] = b0[t] - m * g0[t] * inv;
    }
    __syncthreads();
    if (t < 64) {
        float acc = b1[t];
#pragma unroll
        for (int f = 0; f < 7; ++f) {
            W1p[f * 64 + t] = W1[f * 64 + t] * sc[f];
            acc += sh[f] * W1[f * 64 + t];
        }
        b1p[t] = acc;
    }
}

__global__ void prep_bn_kernel(const float* __restrict__ sum, const float* __restrict__ sq,
                               const float* __restrict__ g, const float* __restrict__ b,
                               float* __restrict__ sc, float* __restrict__ sh, int C)
{
    int c = blockIdx.x * blockDim.x + threadIdx.x;
    if (c < C) {
        float m = sum[c] / (float)NPTS;
        float v = sq[c] / (float)NPTS - m * m;
        float inv = 1.0f / sqrtf(fmaxf(v, 0.f) + EPSB);
        sc[c] = g[c] * inv;
        sh[c] = b[c] - m * g[c] * inv;
    }
}

// ---- standalone bn+relu elementwise pass (in place, bf16x8 per thread) ----
template<int C>
__global__ __launch_bounds__(256) void bn_apply_kernel(
    unsigned short* __restrict__ y, const float* __restrict__ sc, const float* __restrict__ sh)
{
    __shared__ float scl[C], shl[C];
    int t = threadIdx.x;
    for (int i = t; i < C; i += 256) { scl[i] = sc[i]; shl[i] = sh[i]; }
    __syncthreads();
    size_t i8 = ((size_t)blockIdx.x * 256 + t) * 8;   // grid sized exactly MPAD*C/2048
    int col = (int)(i8 & (size_t)(C - 1));
    uint4 v = *(const uint4*)(y + i8);
    v.x = bnrelu_pack(v.x, scl[col+0], shl[col+0], scl[col+1], shl[col+1]);
    v.y = bnrelu_pack(v.y, scl[col+2], shl[col+2], scl[col+3], shl[col+3]);
    v.z = bnrelu_pack(v.z, scl[col+4], shl[col+4], scl[col+5], shl[col+5]);
    v.w = bnrelu_pack(v.w, scl[col+6], shl[col+6], scl[col+7], shl[col+7]);
    *(uint4*)(y + i8) = v;
}

// ---- weight transpose+cast: Wt[n][k] = bf16(W[k][n]) ----
__global__ __launch_bounds__(256) void wtrans_kernel(const float* __restrict__ W,
                                                     unsigned short* __restrict__ Wt,
                                                     int K, int N)
{
    int i = blockIdx.x * 256 + threadIdx.x;
    if (i < K * N) {
        int k = i / N, n = i % N;
        Wt[(size_t)n * K + k] = f2bf(W[i]);
    }
}

// ---- layer 1: y1(bf16) = fea @ W1' + b1' (K=7, Nc=64) + fp32 col stats ----
__global__ __launch_bounds__(256) void layer1_kernel(
    const float* __restrict__ fea, const float* __restrict__ W1p, const float* __restrict__ b1p,
    unsigned short* __restrict__ y1, float* __restrict__ sum1, float* __restrict__ sq1)
{
    __shared__ float Wl[448], bl[64], feaL[448];
    __shared__ float red[4][64];
    int t = threadIdx.x;
    int p0 = blockIdx.x * 64;
    for (int i = t; i < 448; i += 256) { Wl[i] = W1p[i]; feaL[i] = fea[(size_t)p0 * 7 + i]; }
    if (t < 64) bl[t] = b1p[t];
    __syncthreads();
    int c = t & 63, pr = t >> 6;
    float s = 0.f, q = 0.f;
#pragma unroll
    for (int it = 0; it < 16; ++it) {
        int pl = it * 4 + pr;
        float v = bl[c];
#pragma unroll
        for (int f = 0; f < 7; ++f) v = fmaf(feaL[pl * 7 + f], Wl[f * 64 + c], v);
        y1[(size_t)(p0 + pl) * 64 + c] = f2bf(v);
        s += v; q += v * v;
    }
    red[pr][c] = s; __syncthreads();
    if (t < 64) atomicAdd(&sum1[c], red[0][c] + red[1][c] + red[2][c] + red[3][c]);
    __syncthreads();
    red[pr][c] = q; __syncthreads();
    if (t < 64) atomicAdd(&sq1[c], red[0][c] + red[1][c] + red[2][c] + red[3][c]);
}

// ---- MFMA GEMM v7: 128x128 block of 4 wave-private 64x64 quadrants ----
// No barriers in the K-loop (s_waitcnt only). Wave (wr,wc) loads its own A/B
// into a private 8KB slab; duplicate A (and B) addresses across waves are
// L1/MSHR-merged. Grid = (NC/128, M/128), col-block fastest for L2 A-reuse.
template<int K, int NC, bool STATS>
__global__ __launch_bounds__(256) void gemm_quad(
    const unsigned short* __restrict__ A, const unsigned short* __restrict__ Wt,
    const float* __restrict__ bias, unsigned short* __restrict__ Y,
    float* __restrict__ osum, float* __restrict__ osq)
{
    __shared__ __align__(16) unsigned short lds[4 * 4096];  // 8KB per wave
    __shared__ float colsum[128], colsq[128];
    int t = threadIdx.x;
    int w = t >> 6, ln = t & 63, quad = ln >> 4, lr = ln & 15;
    int wr = w >> 1, wc = w & 1;
    int mb = blockIdx.y * 128 + wr * 64;          // this wave's 64 rows
    int cb = blockIdx.x * 128 + wc * 64;          // this wave's 64 cols
    unsigned short* Aw = lds + w * 4096;          // [64][32] ushort
    unsigned short* Bw = Aw + 2048;

    if (STATS) {
        if (t < 128) { colsum[t] = 0.f; colsq[t] = 0.f; }
        __syncthreads();                           // once, before K-loop
    }

    const int grow4 = ln >> 2, koff = (ln & 3) * 8;   // 4 lanes per row, 8 bf16 each
    f32x4 acc[4][4];
#pragma unroll
    for (int i = 0; i < 4; ++i)
#pragma unroll
        for (int j = 0; j < 4; ++j) acc[i][j] = (f32x4){0.f, 0.f, 0.f, 0.f};

    for (int kt = 0; kt < K; kt += 32) {
#pragma unroll
        for (int i = 0; i < 4; ++i) {              // A: 64 rows x 32 k, wave-private
            async16(A + (size_t)(mb + i * 16 + grow4) * K + kt + koff,
                    Aw + i * 512 + ln * 8);
            async16(Wt + (size_t)(cb + i * 16 + grow4) * K + kt + koff,
                    Bw + i * 512 + ln * 8);
        }
        asm volatile("s_waitcnt vmcnt(0)" ::: "memory");
        short8 af[4], bfr[4];
#pragma unroll
        for (int mi = 0; mi < 4; ++mi)
            af[mi] = *(const short8*)&Aw[(mi * 16 + lr) * 32 + quad * 8];
#pragma unroll
        for (int ni = 0; ni < 4; ++ni)
            bfr[ni] = *(const short8*)&Bw[(ni * 16 + lr) * 32 + quad * 8];
        asm volatile("s_waitcnt lgkmcnt(0)" ::: "memory");  // frags read before re-stage
#pragma unroll
        for (int mi = 0; mi < 4; ++mi)
#pragma unroll
            for (int ni = 0; ni < 4; ++ni)
                acc[mi][ni] = __builtin_amdgcn_mfma_f32_16x16x32_bf16(
                    af[mi], bfr[ni], acc[mi][ni], 0, 0, 0);
    }

    // wave-private epilogue: C-stage 64x64 bf16 in own slab (A+B dead), no barriers
    unsigned short* Cw = Aw;                       // 8KB = 64*64 ushort exactly
    // C/D layout: col=lane&15, row=quad*4+reg
#pragma unroll
    for (int ni = 0; ni < 4; ++ni) {
        int col = ni * 16 + lr;
        float bv = bias[cb + col];
        float s = 0.f, q = 0.f;
#pragma unroll
        for (int mi = 0; mi < 4; ++mi) {
            int rb = mi * 16 + quad * 4;
#pragma unroll
            for (int r = 0; r < 4; ++r) {
                float v = acc[mi][ni][r] + bv;
                Cw[(rb + r) * 64 + col] = f2bf(v);
                if (STATS && (mb + rb + r) < NPTS) { s += v; q += v * v; }
            }
        }
        if (STATS) {
            atomicAdd(&colsum[wc * 64 + col], s);  // LDS atomics, no barrier needed
            atomicAdd(&colsq[wc * 64 + col], q);
        }
    }
#pragma unroll
    for (int i = 0; i < 8; ++i) {                  // 64x64 tile, full-line uint4 stores
        int idx = i * 64 + ln;
        int row = idx >> 3, colq = (idx & 7) * 8;
        *(uint4*)(Y + (size_t)(mb + row) * NC + cb + colq) = *(const uint4*)&Cw[row * 64 + colq];
    }
    if (STATS) {
        __syncthreads();                           // once, after all waves' LDS atomics
        if (t < 128) {
            atomicAdd(&osum[blockIdx.x * 128 + t], colsum[t]);
            atomicAdd(&osq[blockIdx.x * 128 + t], colsq[t]);
        }
    }
}

// ---- sort machinery: histogram, 3-phase exclusive scan, index scatter ----
__global__ __launch_bounds__(256) void hist_kernel(const int* __restrict__ xy,
                                                   int* __restrict__ cnt)
{
    int p = blockIdx.x * 256 + threadIdx.x;
    if (p < NPTS) {
        int id = xy[(size_t)p * 2] * GYD + xy[(size_t)p * 2 + 1];
        atomicAdd(&cnt[id], 1);
    }
}

__global__ __launch_bounds__(256) void scanA_kernel(const int* __restrict__ cnt,
                                                    int* __restrict__ csum)
{
    __shared__ int red[256];
    int t = threadIdx.x, base = blockIdx.x * 2048;
    int s = 0;
    for (int i = t; i < 2048; i += 256) {
        int idx = base + i;
        if (idx < SEGR) s += cnt[idx];
    }
    red[t] = s; __syncthreads();
    for (int o = 128; o > 0; o >>= 1) { if (t < o) red[t] += red[t + o]; __syncthreads(); }
    if (t == 0) csum[blockIdx.x] = red[0];
}

__global__ void scanB_kernel(int* __restrict__ csum, int* __restrict__ offs)
{
    if (threadIdx.x == 0) {
        int run = 0;
        for (int i = 0; i < 64; ++i) { int v = csum[i]; csum[i] = run; run += v; }
        offs[SEGR] = run;
    }
}

__global__ __launch_bounds__(256) void scanC_kernel(const int* __restrict__ cnt,
                                                    const int* __restrict__ csum,
                                                    int* __restrict__ offs,
                                                    int* __restrict__ cursor)
{
    __shared__ int red[256];
    int t = threadIdx.x, base = blockIdx.x * 2048;
    int v[8]; int s = 0;
#pragma unroll
    for (int i = 0; i < 8; ++i) {
        int idx = base + t * 8 + i;
        v[i] = (idx < SEGR) ? cnt[idx] : 0;
        s += v[i];
    }
    red[t] = s; __syncthreads();
    for (int o = 1; o < 256; o <<= 1) {
        int x = (t >= o) ? red[t - o] : 0;
        __syncthreads();
        red[t] += x;
        __syncthreads();
    }
    int run = red[t] - s + csum[blockIdx.x];
#pragma unroll
    for (int i = 0; i < 8; ++i) {
        int idx = base + t * 8 + i;
        if (idx < SEGR) { offs[idx] = run; cursor[idx] = run; }
        run += v[i];
    }
}

__global__ __launch_bounds__(256) void scatter_idx_kernel(const int* __restrict__ xy,
                                                          int* __restrict__ cursor,
                                                          int* __restrict__ order)
{
    int p = blockIdx.x * 256 + threadIdx.x;
    if (p < NPTS) {
        int id = xy[(size_t)p * 2] * GYD + xy[(size_t)p * 2 + 1];
        int pos = atomicAdd(&cursor[id], 1);
        order[pos] = p;
    }
}

// ---- fused gather-segmax + partial L5: E[cell][32] (+)= max_pts(y4g) @ W5[g-slice] ----
__global__ __launch_bounds__(256) void segmax_l5_kernel(
    const unsigned short* __restrict__ y4g, const unsigned short* __restrict__ Wt5,
    const int* __restrict__ offs, const int* __restrict__ order,
    int g, float* __restrict__ E)
{
    __shared__ __align__(16) unsigned short seg[64 * 136];
    __shared__ __align__(16) unsigned short w5s[32 * 136];
    __shared__ int offs_s[65];
    int t = threadIdx.x;
    int c0 = blockIdx.x * 64;
    if (t < 65) offs_s[t] = offs[c0 + t];
    {   // stage Wt5[n=0..31][k = g*128 .. +128]
        int n = t >> 3, ko = (t & 7) * 16;
        *(uint4*)&w5s[n * 136 + ko]     = *(const uint4*)(Wt5 + (size_t)n * 512 + g * 128 + ko);
        *(uint4*)&w5s[n * 136 + ko + 8] = *(const uint4*)(Wt5 + (size_t)n * 512 + g * 128 + ko + 8);
    }
    __syncthreads();
    int cell = t >> 2, q = t & 3;
    float mx[32];
#pragma unroll
    for (int i = 0; i < 32; ++i) mx[i] = -3.0e38f;
    int jb = offs_s[cell], je = offs_s[cell + 1];
    for (int j = jb; j < je; ++j) {
        int p = order[j];
        const uint4* rp = (const uint4*)(y4g + (size_t)p * 128 + q * 32);
#pragma unroll
        for (int u = 0; u < 4; ++u) {
            uint4 vv = rp[u];
            unsigned int wv[4] = {vv.x, vv.y, vv.z, vv.w};
#pragma unroll
            for (int k2 = 0; k2 < 4; ++k2) {
                int idx = u * 8 + k2 * 2;
                mx[idx]     = fmaxf(mx[idx],     bf2f((unsigned short)(wv[k2] & 0xffffu)));
                mx[idx + 1] = fmaxf(mx[idx + 1], bf2f((unsigned short)(wv[k2] >> 16)));
            }
        }
    }
    bool empty = (jb == je);
#pragma unroll
    for (int i = 0; i < 16; ++i) {
        float lo = empty ? 0.f : mx[2 * i], hi = empty ? 0.f : mx[2 * i + 1];
        unsigned int pk = (unsigned int)f2bf(lo) | ((unsigned int)f2bf(hi) << 16);
        *(unsigned int*)&seg[cell * 136 + q * 32 + 2 * i] = pk;
    }
    __syncthreads();
    int lane = t & 63, w = t >> 6, quad = lane >> 4, lr = lane & 15;
    f32x4 acc[2];
    acc[0] = (f32x4){0.f, 0.f, 0.f, 0.f};
    acc[1] = (f32x4){0.f, 0.f, 0.f, 0.f};
#pragma unroll
    for (int kt = 0; kt < 4; ++kt) {
        short8 af = *(const short8*)&seg[(w * 16 + lr) * 136 + kt * 32 + quad * 8];
#pragma unroll
        for (int ni = 0; ni < 2; ++ni) {
            short8 bfr = *(const short8*)&w5s[(ni * 16 + lr) * 136 + kt * 32 + quad * 8];
            acc[ni] = __builtin_amdgcn_mfma_f32_16x16x32_bf16(af, bfr, acc[ni], 0, 0, 0);
        }
    }
#pragma unroll
    for (int ni = 0; ni < 2; ++ni) {
        int h = ni * 16 + lr;
#pragma unroll
        for (int r = 0; r < 4; ++r) {
            int cr = w * 16 + quad * 4 + r;
            float* ep = E + (size_t)(c0 + cr) * 32 + h;
            float v = acc[ni][r];
            if (g > 0) v += *ep;
            *ep = v;
        }
    }
}

// ---- output: out[h][cell] = occ ? relu(E[cell][h] + b5[h]) : 0 ----
__global__ __launch_bounds__(256) void out_kernel(
    const float* __restrict__ E, const int* __restrict__ cnt,
    const float* __restrict__ b5, float* __restrict__ out)
{
    int t = threadIdx.x;
    int c0 = blockIdx.x * 64;
    int lane = t & 63, hq = t >> 6;
    int cell = c0 + lane;
    if (c0 >= SEGR) {
#pragma unroll
        for (int j = 0; j < 8; ++j)
            out[(size_t)(hq * 8 + j) * NSEG + cell] = 0.f;
        return;
    }
    bool oc = cnt[cell] > 0;
    float4 e0 = *(const float4*)(E + (size_t)cell * 32 + hq * 8);
    float4 e1 = *(const float4*)(E + (size_t)cell * 32 + hq * 8 + 4);
    float r[8] = {e0.x, e0.y, e0.z, e0.w, e1.x, e1.y, e1.z, e1.w};
#pragma unroll
    for (int j = 0; j < 8; ++j) {
        float v = oc ? fmaxf(r[j] + b5[hq * 8 + j], 0.f) : 0.f;
        out[(size_t)(hq * 8 + j) * NSEG + cell] = v;
    }
}

extern "C" void kernel_launch(void* const* d_in, const int* in_sizes, int n_in,
                              void* d_out, int out_size, void* d_ws, size_t ws_size,
                              hipStream_t stream)
{
    const float* pt_fea = (const float*)d_in[0];
    const int*   xy_ind = (const int*)d_in[1];
    const float* bn0_g  = (const float*)d_in[2];
    const float* bn0_b  = (const float*)d_in[3];
    const float* W1     = (const float*)d_in[4];
    const float* b1     = (const float*)d_in[5];
    const float* bn1_g  = (const float*)d_in[6];
    const float* bn1_b  = (const float*)d_in[7];
    const float* W2     = (const float*)d_in[8];
    const float* b2     = (const float*)d_in[9];
    const float* bn2_g  = (const float*)d_in[10];
    const float* bn2_b  = (const float*)d_in[11];
    const float* W3     = (const float*)d_in[12];
    const float* b3     = (const float*)d_in[13];
    const float* bn3_g  = (const float*)d_in[14];
    const float* bn3_b  = (const float*)d_in[15];
    const float* W4     = (const float*)d_in[16];
    const float* b4     = (const float*)d_in[17];
    const float* W5     = (const float*)d_in[18];
    const float* b5     = (const float*)d_in[19];
    float* out = (float*)d_out;

    // ---- workspace layout (~111 MB, unchanged from R4..R9) ----
    const size_t oY2   = 61472768;                 // MPAD*256*2
    const size_t oE    = oY2 + (size_t)MPAD * 128 * 2;
    const size_t oCnt  = oE + (size_t)SEGR * 32 * 4;
    const size_t oOffs = oCnt + 518400;
    const size_t oCur  = oOffs + 518528;
    const size_t oOrd  = oCur + 518400;
    const size_t oCsum = oOrd + 480000;
    const size_t oSt   = oCsum + 512;
    const size_t oWt2  = oSt + 16384;
    const size_t oWt3  = oWt2 + 16384;
    const size_t oWt4  = oWt3 + 65536;
    const size_t oWt5  = oWt4 + 262144;

    unsigned short* y1   = (unsigned short*)d_ws;
    unsigned short* y3   = (unsigned short*)d_ws;
    unsigned short* y2   = (unsigned short*)((char*)d_ws + oY2);
    unsigned short* y4g  = (unsigned short*)((char*)d_ws + oY2);
    float*          E    = (float*)((char*)d_ws + oE);
    int*            cnt  = (int*)((char*)d_ws + oCnt);
    int*            offs = (int*)((char*)d_ws + oOffs);
    int*            cur  = (int*)((char*)d_ws + oCur);
    int*            ord  = (int*)((char*)d_ws + oOrd);
    int*            csum = (int*)((char*)d_ws + oCsum);
    float*          st   = (float*)((char*)d_ws + oSt);
    unsigned short* Wt2  = (unsigned short*)((char*)d_ws + oWt2);
    unsigned short* Wt3  = (unsigned short*)((char*)d_ws + oWt3);
    unsigned short* Wt4  = (unsigned short*)((char*)d_ws + oWt4);
    unsigned short* Wt5  = (unsigned short*)((char*)d_ws + oWt5);

    float* s0 = st + 0;     float* q0 = st + 8;
    float* W1p = st + 16;   float* b1p = st + 464;
    float* sum1 = st + 528; float* sq1 = st + 592; float* sc1 = st + 656; float* sh1 = st + 720;
    float* sum2 = st + 784; float* sq2 = st + 912; float* sc2 = st + 1040; float* sh2 = st + 1168;
    float* sum3 = st + 1296; float* sq3 = st + 1552; float* sc3 = st + 1808; float* sh3 = st + 2064;

    const int MB128 = MPAD / 128;   // 938

    wtrans_kernel<<<(64 * 128 + 255) / 256, 256, 0, stream>>>(W2, Wt2, 64, 128);
    wtrans_kernel<<<(128 * 256 + 255) / 256, 256, 0, stream>>>(W3, Wt3, 128, 256);
    wtrans_kernel<<<(256 * 512 + 255) / 256, 256, 0, stream>>>(W4, Wt4, 256, 512);
    wtrans_kernel<<<(512 * 32 + 255) / 256, 256, 0, stream>>>(W5, Wt5, 512, 32);

    for (int b = 0; b < 2; ++b) {
        const float* fea_b = pt_fea + (size_t)b * NPTS * 7;
        const int*   xy_b  = xy_ind + (size_t)b * NPTS * 2;
        float*       out_b = out + (size_t)b * NHD * NSEG;

        (void)hipMemsetAsync(st, 0, 2320 * sizeof(float), stream);
        (void)hipMemsetAsync(cnt, 0, (size_t)SEGR * 4, stream);

        bn0_stats_kernel<<<128, 256, 0, stream>>>(fea_b, s0, q0);
        prep0_kernel<<<1, 64, 0, stream>>>(s0, q0, bn0_g, bn0_b, W1, b1, W1p, b1p);
        layer1_kernel<<<NPTS / 64, 256, 0, stream>>>(fea_b, W1p, b1p, y1, sum1, sq1);
        prep_bn_kernel<<<1, 64, 0, stream>>>(sum1, sq1, bn1_g, bn1_b, sc1, sh1, 64);
        bn_apply_kernel<64><<<MPAD / 32, 256, 0, stream>>>(y1, sc1, sh1);
        gemm_quad<64, 128, true><<<dim3(1, MB128), 256, 0, stream>>>(
            y1, Wt2, b2, y2, sum2, sq2);
        prep_bn_kernel<<<1, 128, 0, stream>>>(sum2, sq2, bn2_g, bn2_b, sc2, sh2, 128);
        bn_apply_kernel<128><<<MPAD / 16, 256, 0, stream>>>(y2, sc2, sh2);
        gemm_quad<128, 256, true><<<dim3(2, MB128), 256, 0, stream>>>(
            y2, Wt3, b3, y3, sum3, sq3);
        prep_bn_kernel<<<1, 256, 0, stream>>>(sum3, sq3, bn3_g, bn3_b, sc3, sh3, 256);
        bn_apply_kernel<256><<<MPAD / 8, 256, 0, stream>>>(y3, sc3, sh3);

        hist_kernel<<<(NPTS + 255) / 256, 256, 0, stream>>>(xy_b, cnt);
        scanA_kernel<<<64, 256, 0, stream>>>(cnt, csum);
        scanB_kernel<<<1, 64, 0, stream>>>(csum, offs);
        scanC_kernel<<<64, 256, 0, stream>>>(cnt, csum, offs, cur);
        scatter_idx_kernel<<<(NPTS + 255) / 256, 256, 0, stream>>>(xy_b, cur, ord);

        for (int g = 0; g < 4; ++g) {
            gemm_quad<256, 128, false><<<dim3(1, MB128), 256, 0, stream>>>(
                y3, Wt4 + (size_t)g * 128 * 256, b4 + g * 128, y4g, nullptr, nullptr);
            segmax_l5_kernel<<<SEGR / 64, 256, 0, stream>>>(y4g, Wt5, offs, ord, g, E);
        }
        out_kernel<<<NSEG / 64, 256, 0, stream>>>(E, cnt, b5, out_b);
    }
}

// Round 11
// 881.347 us; speedup vs baseline: 1.1826x; 1.0546x over previous
//
#include <hip/hip_runtime.h>
#include <cstdint>

#define GXD 480
#define GYD 360
#define NHD 32
#define NPTS 120000
#define MPAD 120064           // NPTS padded to multiple of 256 (469*256)
#define SEGR 129600           // 360*360 possible ids
#define NSEG (GXD*GYD)        // 172800
#define EPSB 1e-5f

using short8 = __attribute__((ext_vector_type(8))) short;   // 8 bf16 in 4 VGPRs
using f32x4  = __attribute__((ext_vector_type(4))) float;   // MFMA accumulator

// ---- bf16 helpers ----
__device__ __forceinline__ float bf2f(unsigned short u) {
    return __uint_as_float(((unsigned int)u) << 16);
}
__device__ __forceinline__ unsigned short f2bf(float f) {
    unsigned int u = __float_as_uint(f);
    u += 0x7fffu + ((u >> 16) & 1u);   // round-to-nearest-even
    return (unsigned short)(u >> 16);
}
__device__ __forceinline__ unsigned int bnrelu_pack(unsigned int wv, float sc0, float sh0,
                                                    float sc1, float sh1)
{
    float lo = fmaxf(fmaf(bf2f((unsigned short)(wv & 0xffffu)), sc0, sh0), 0.f);
    float hi = fmaxf(fmaf(bf2f((unsigned short)(wv >> 16)), sc1, sh1), 0.f);
    return (unsigned int)f2bf(lo) | ((unsigned int)f2bf(hi) << 16);
}
// bn+relu applied to an 8-element bf16 A-fragment (k-ascending)
__device__ __forceinline__ short8 bn_frag(short8 a, float4 s0, float4 s1,
                                          float4 h0, float4 h1)
{
    union { short8 v; uint4 u; } in, out;
    in.v = a;
    out.u.x = bnrelu_pack(in.u.x, s0.x, h0.x, s0.y, h0.y);
    out.u.y = bnrelu_pack(in.u.y, s0.z, h0.z, s0.w, h0.w);
    out.u.z = bnrelu_pack(in.u.z, s1.x, h1.x, s1.y, h1.y);
    out.u.w = bnrelu_pack(in.u.w, s1.z, h1.z, s1.w, h1.w);
    return out.v;
}

// ---- async global->LDS, 16B per lane (dest = wave-uniform base + lane*16) ----
__device__ __forceinline__ void async16(const unsigned short* g, unsigned short* l)
{
    __builtin_amdgcn_global_load_lds(
        (const __attribute__((address_space(1))) unsigned int*)g,
        (__attribute__((address_space(3))) unsigned int*)l, 16, 0, 0);
}

// ---- bn0 stats ----
__global__ __launch_bounds__(256) void bn0_stats_kernel(
    const float* __restrict__ fea, float* __restrict__ s0, float* __restrict__ q0)
{
    float s[7] = {0,0,0,0,0,0,0}, q[7] = {0,0,0,0,0,0,0};
    for (int p = blockIdx.x * 256 + threadIdx.x; p < NPTS; p += gridDim.x * 256) {
        const float* r = fea + (size_t)p * 7;
#pragma unroll
        for (int f = 0; f < 7; ++f) { float v = r[f]; s[f] += v; q[f] += v * v; }
    }
    __shared__ float red[256];
    int t = threadIdx.x;
#pragma unroll
    for (int f = 0; f < 7; ++f) {
        red[t] = s[f]; __syncthreads();
        for (int o = 128; o > 0; o >>= 1) {
            if (t < o) red[t] += red[t + o];
            __syncthreads();
        }
        if (t == 0) atomicAdd(&s0[f], red[0]);
        __syncthreads();
        red[t] = q[f]; __syncthreads();
        for (int o = 128; o > 0; o >>= 1) {
            if (t < o) red[t] += red[t + o];
            __syncthreads();
        }
        if (t == 0) atomicAdd(&q0[f], red[0]);
        __syncthreads();
    }
}

// ---- fold bn0 into W1 ----
__global__ void prep0_kernel(const float* __restrict__ s0, const float* __restrict__ q0,
                             const float* __restrict__ g0, const float* __restrict__ b0,
                             const float* __restrict__ W1, const float* __restrict__ b1,
                             float* __restrict__ W1p, float* __restrict__ b1p)
{
    __shared__ float sc[7], sh[7];
    int t = threadIdx.x;
    if (t < 7) {
        float m = s0[t] / (float)NPTS;
        float v = q0[t] / (float)NPTS - m * m;
        float inv = 1.0f / sqrtf(fmaxf(v, 0.f) + EPSB);
        sc[t] = g0[t] * inv;
        sh[t] = b0[t] - m * g0[t] * inv;
    }
    __syncthreads();
    if (t < 64) {
        float acc = b1[t];
#pragma unroll
        for (int f = 0; f < 7; ++f) {
            W1p[f * 64 + t] = W1[f * 64 + t] * sc[f];
            acc += sh[f] * W1[f * 64 + t];
        }
        b1p[t] = acc;
    }
}

__global__ void prep_bn_kernel(const float* __restrict__ sum, const float* __restrict__ sq,
                               const float* __restrict__ g, const float* __restrict__ b,
                               float* __restrict__ sc, float* __restrict__ sh, int C)
{
    int c = blockIdx.x * blockDim.x + threadIdx.x;
    if (c < C) {
        float m = sum[c] / (float)NPTS;
        float v = sq[c] / (float)NPTS - m * m;
        float inv = 1.0f / sqrtf(fmaxf(v, 0.f) + EPSB);
        sc[c] = g[c] * inv;
        sh[c] = b[c] - m * g[c] * inv;
    }
}

// ---- weight transpose+cast: Wt[n][k] = bf16(W[k][n]) ----
__global__ __launch_bounds__(256) void wtrans_kernel(const float* __restrict__ W,
                                                     unsigned short* __restrict__ Wt,
                                                     int K, int N)
{
    int i = blockIdx.x * 256 + threadIdx.x;
    if (i < K * N) {
        int k = i / N, n = i % N;
        Wt[(size_t)n * K + k] = f2bf(W[i]);
    }
}

// ---- layer 1 v2: y1(bf16) = fea @ W1' + b1' (K=7, Nc=64) + fp32 col stats ----
// 256 points/block; thread = (point pt, col-group cg of 8). Full-line uint4
// stores; stats via wave shfl_xor butterfly -> few atomics.
__global__ __launch_bounds__(256) void layer1_kernel(
    const float* __restrict__ fea, const float* __restrict__ W1p, const float* __restrict__ b1p,
    unsigned short* __restrict__ y1, float* __restrict__ sum1, float* __restrict__ sq1)
{
    __shared__ float Wl[448], bl[64];
    __shared__ float feaL[256 * 7];
    __shared__ float colsum[64], colsq[64];
    int t = threadIdx.x;
    int p0 = blockIdx.x * 256;
    for (int i = t; i < 448; i += 256) Wl[i] = W1p[i];
    if (t < 64) { bl[t] = b1p[t]; colsum[t] = 0.f; colsq[t] = 0.f; }
    int nval7 = (NPTS - p0) * 7;                 // valid feature words in this block
    for (int i = t; i < 256 * 7; i += 256)
        feaL[i] = (i < nval7) ? fea[(size_t)p0 * 7 + i] : 0.f;
    __syncthreads();
    int cg = t & 7, pt = t >> 3;                 // 8 col-groups x 32 point-threads
    float s[8] = {}, q[8] = {};
#pragma unroll
    for (int it = 0; it < 8; ++it) {
        int row = it * 32 + pt;
        bool valid = (p0 + row) < NPTS;
        float f[7];
#pragma unroll
        for (int ff = 0; ff < 7; ++ff) f[ff] = feaL[row * 7 + ff];
        float vj[8];
#pragma unroll
        for (int j = 0; j < 8; ++j) {
            int c = cg * 8 + j;
            float v = bl[c];
#pragma unroll
            for (int ff = 0; ff < 7; ++ff) v = fmaf(f[ff], Wl[ff * 64 + c], v);
            vj[j] = v;
            if (valid) { s[j] += v; q[j] += v * v; }
        }
        uint4 ow;
        ow.x = (unsigned int)f2bf(vj[0]) | ((unsigned int)f2bf(vj[1]) << 16);
        ow.y = (unsigned int)f2bf(vj[2]) | ((unsigned int)f2bf(vj[3]) << 16);
        ow.z = (unsigned int)f2bf(vj[4]) | ((unsigned int)f2bf(vj[5]) << 16);
        ow.w = (unsigned int)f2bf(vj[6]) | ((unsigned int)f2bf(vj[7]) << 16);
        *(uint4*)(y1 + (size_t)(p0 + row) * 64 + cg * 8) = ow;
    }
    // wave butterfly over the pt bits within each wave (lanes differ in bits 3..5)
#pragma unroll
    for (int off = 8; off < 64; off <<= 1) {
#pragma unroll
        for (int j = 0; j < 8; ++j) {
            s[j] += __shfl_xor(s[j], off);
            q[j] += __shfl_xor(q[j], off);
        }
    }
    if ((t & 63) < 8) {                          // one leader per cg per wave
#pragma unroll
        for (int j = 0; j < 8; ++j) {
            atomicAdd(&colsum[cg * 8 + j], s[j]);
            atomicAdd(&colsq[cg * 8 + j], q[j]);
        }
    }
    __syncthreads();
    if (t < 64) {
        atomicAdd(&sum1[t], colsum[t]);
        atomicAdd(&sq1[t], colsq[t]);
    }
}

// ---- MFMA GEMM v8: quadrant wave-private + fused BN+ReLU on A-fragments ----
// Y = relu(A*sc+sh) @ Wt^T + bias. No barriers in K-loop; bn applied in regs
// at frag-read time (A-frag layout: k = quad*8 + j).
template<int K, int NC, bool STATS>
__global__ __launch_bounds__(256) void gemm_quad(
    const unsigned short* __restrict__ A, const unsigned short* __restrict__ Wt,
    const float* __restrict__ scale, const float* __restrict__ shift,
    const float* __restrict__ bias, unsigned short* __restrict__ Y,
    float* __restrict__ osum, float* __restrict__ osq)
{
    __shared__ __align__(16) unsigned short lds[4 * 4096];  // 8KB per wave
    __shared__ float scs[K], shs[K];
    __shared__ float colsum[128], colsq[128];
    int t = threadIdx.x;
    int w = t >> 6, ln = t & 63, quad = ln >> 4, lr = ln & 15;
    int wr = w >> 1, wc = w & 1;
    int mb = blockIdx.y * 128 + wr * 64;          // this wave's 64 rows
    int cb = blockIdx.x * 128 + wc * 64;          // this wave's 64 cols
    unsigned short* Aw = lds + w * 4096;          // [64][32] ushort
    unsigned short* Bw = Aw + 2048;

    for (int i = t; i < K; i += 256) { scs[i] = scale[i]; shs[i] = shift[i]; }
    if (STATS && t < 128) { colsum[t] = 0.f; colsq[t] = 0.f; }
    __syncthreads();                               // once, before K-loop

    const int grow4 = ln >> 2, koff = (ln & 3) * 8;
    f32x4 acc[4][4];
#pragma unroll
    for (int i = 0; i < 4; ++i)
#pragma unroll
        for (int j = 0; j < 4; ++j) acc[i][j] = (f32x4){0.f, 0.f, 0.f, 0.f};

    for (int kt = 0; kt < K; kt += 32) {
#pragma unroll
        for (int i = 0; i < 4; ++i) {              // A/B: 64 rows x 32 k, wave-private
            async16(A + (size_t)(mb + i * 16 + grow4) * K + kt + koff,
                    Aw + i * 512 + ln * 8);
            async16(Wt + (size_t)(cb + i * 16 + grow4) * K + kt + koff,
                    Bw + i * 512 + ln * 8);
        }
        int k0 = kt + quad * 8;                    // this lane's A-frag k-base
        float4 s0 = *(const float4*)&scs[k0];
        float4 s1 = *(const float4*)&scs[k0 + 4];
        float4 h0 = *(const float4*)&shs[k0];
        float4 h1 = *(const float4*)&shs[k0 + 4];
        asm volatile("s_waitcnt vmcnt(0)" ::: "memory");
        short8 af[4], bfr[4];
#pragma unroll
        for (int mi = 0; mi < 4; ++mi)
            af[mi] = *(const short8*)&Aw[(mi * 16 + lr) * 32 + quad * 8];
#pragma unroll
        for (int ni = 0; ni < 4; ++ni)
            bfr[ni] = *(const short8*)&Bw[(ni * 16 + lr) * 32 + quad * 8];
        asm volatile("s_waitcnt lgkmcnt(0)" ::: "memory");  // frags read before re-stage
#pragma unroll
        for (int mi = 0; mi < 4; ++mi)
            af[mi] = bn_frag(af[mi], s0, s1, h0, h1);
#pragma unroll
        for (int mi = 0; mi < 4; ++mi)
#pragma unroll
            for (int ni = 0; ni < 4; ++ni)
                acc[mi][ni] = __builtin_amdgcn_mfma_f32_16x16x32_bf16(
                    af[mi], bfr[ni], acc[mi][ni], 0, 0, 0);
    }

    // wave-private epilogue: C-stage 64x64 bf16 in own slab (A+B dead), no barriers
    unsigned short* Cw = Aw;
    // C/D layout: col=lane&15, row=quad*4+reg
#pragma unroll
    for (int ni = 0; ni < 4; ++ni) {
        int col = ni * 16 + lr;
        float bv = bias[cb + col];
        float s = 0.f, q = 0.f;
#pragma unroll
        for (int mi = 0; mi < 4; ++mi) {
            int rb = mi * 16 + quad * 4;
#pragma unroll
            for (int r = 0; r < 4; ++r) {
                float v = acc[mi][ni][r] + bv;
                Cw[(rb + r) * 64 + col] = f2bf(v);
                if (STATS && (mb + rb + r) < NPTS) { s += v; q += v * v; }
            }
        }
        if (STATS) {
            atomicAdd(&colsum[wc * 64 + col], s);
            atomicAdd(&colsq[wc * 64 + col], q);
        }
    }
#pragma unroll
    for (int i = 0; i < 8; ++i) {                  // 64x64 tile, full-line uint4 stores
        int idx = i * 64 + ln;
        int row = idx >> 3, colq = (idx & 7) * 8;
        *(uint4*)(Y + (size_t)(mb + row) * NC + cb + colq) = *(const uint4*)&Cw[row * 64 + colq];
    }
    if (STATS) {
        __syncthreads();                           // once, after all waves' LDS atomics
        if (t < 128) {
            atomicAdd(&osum[blockIdx.x * 128 + t], colsum[t]);
            atomicAdd(&osq[blockIdx.x * 128 + t], colsq[t]);
        }
    }
}

// ---- sort machinery: histogram, 3-phase exclusive scan, index scatter ----
__global__ __launch_bounds__(256) void hist_kernel(const int* __restrict__ xy,
                                                   int* __restrict__ cnt)
{
    int p = blockIdx.x * 256 + threadIdx.x;
    if (p < NPTS) {
        int id = xy[(size_t)p * 2] * GYD + xy[(size_t)p * 2 + 1];
        atomicAdd(&cnt[id], 1);
    }
}

__global__ __launch_bounds__(256) void scanA_kernel(const int* __restrict__ cnt,
                                                    int* __restrict__ csum)
{
    __shared__ int red[256];
    int t = threadIdx.x, base = blockIdx.x * 2048;
    int s = 0;
    for (int i = t; i < 2048; i += 256) {
        int idx = base + i;
        if (idx < SEGR) s += cnt[idx];
    }
    red[t] = s; __syncthreads();
    for (int o = 128; o > 0; o >>= 1) { if (t < o) red[t] += red[t + o]; __syncthreads(); }
    if (t == 0) csum[blockIdx.x] = red[0];
}

__global__ void scanB_kernel(int* __restrict__ csum, int* __restrict__ offs)
{
    if (threadIdx.x == 0) {
        int run = 0;
        for (int i = 0; i < 64; ++i) { int v = csum[i]; csum[i] = run; run += v; }
        offs[SEGR] = run;
    }
}

__global__ __launch_bounds__(256) void scanC_kernel(const int* __restrict__ cnt,
                                                    const int* __restrict__ csum,
                                                    int* __restrict__ offs,
                                                    int* __restrict__ cursor)
{
    __shared__ int red[256];
    int t = threadIdx.x, base = blockIdx.x * 2048;
    int v[8]; int s = 0;
#pragma unroll
    for (int i = 0; i < 8; ++i) {
        int idx = base + t * 8 + i;
        v[i] = (idx < SEGR) ? cnt[idx] : 0;
        s += v[i];
    }
    red[t] = s; __syncthreads();
    for (int o = 1; o < 256; o <<= 1) {
        int x = (t >= o) ? red[t - o] : 0;
        __syncthreads();
        red[t] += x;
        __syncthreads();
    }
    int run = red[t] - s + csum[blockIdx.x];
#pragma unroll
    for (int i = 0; i < 8; ++i) {
        int idx = base + t * 8 + i;
        if (idx < SEGR) { offs[idx] = run; cursor[idx] = run; }
        run += v[i];
    }
}

__global__ __launch_bounds__(256) void scatter_idx_kernel(const int* __restrict__ xy,
                                                          int* __restrict__ cursor,
                                                          int* __restrict__ order)
{
    int p = blockIdx.x * 256 + threadIdx.x;
    if (p < NPTS) {
        int id = xy[(size_t)p * 2] * GYD + xy[(size_t)p * 2 + 1];
        int pos = atomicAdd(&cursor[id], 1);
        order[pos] = p;
    }
}

// ---- fused gather-segmax + partial L5: E[cell][32] (+)= max_pts(y4g) @ W5[g-slice] ----
__global__ __launch_bounds__(256) void segmax_l5_kernel(
    const unsigned short* __restrict__ y4g, const unsigned short* __restrict__ Wt5,
    const int* __restrict__ offs, const int* __restrict__ order,
    int g, float* __restrict__ E)
{
    __shared__ __align__(16) unsigned short seg[64 * 136];
    __shared__ __align__(16) unsigned short w5s[32 * 136];
    __shared__ int offs_s[65];
    int t = threadIdx.x;
    int c0 = blockIdx.x * 64;
    if (t < 65) offs_s[t] = offs[c0 + t];
    {   // stage Wt5[n=0..31][k = g*128 .. +128]
        int n = t >> 3, ko = (t & 7) * 16;
        *(uint4*)&w5s[n * 136 + ko]     = *(const uint4*)(Wt5 + (size_t)n * 512 + g * 128 + ko);
        *(uint4*)&w5s[n * 136 + ko + 8] = *(const uint4*)(Wt5 + (size_t)n * 512 + g * 128 + ko + 8);
    }
    __syncthreads();
    int cell = t >> 2, q = t & 3;
    float mx[32];
#pragma unroll
    for (int i = 0; i < 32; ++i) mx[i] = -3.0e38f;
    int jb = offs_s[cell], je = offs_s[cell + 1];
    for (int j = jb; j < je; ++j) {
        int p = order[j];
        const uint4* rp = (const uint4*)(y4g + (size_t)p * 128 + q * 32);
#pragma unroll
        for (int u = 0; u < 4; ++u) {
            uint4 vv = rp[u];
            unsigned int wv[4] = {vv.x, vv.y, vv.z, vv.w};
#pragma unroll
            for (int k2 = 0; k2 < 4; ++k2) {
                int idx = u * 8 + k2 * 2;
                mx[idx]     = fmaxf(mx[idx],     bf2f((unsigned short)(wv[k2] & 0xffffu)));
                mx[idx + 1] = fmaxf(mx[idx + 1], bf2f((unsigned short)(wv[k2] >> 16)));
            }
        }
    }
    bool empty = (jb == je);
#pragma unroll
    for (int i = 0; i < 16; ++i) {
        float lo = empty ? 0.f : mx[2 * i], hi = empty ? 0.f : mx[2 * i + 1];
        unsigned int pk = (unsigned int)f2bf(lo) | ((unsigned int)f2bf(hi) << 16);
        *(unsigned int*)&seg[cell * 136 + q * 32 + 2 * i] = pk;
    }
    __syncthreads();
    int lane = t & 63, w = t >> 6, quad = lane >> 4, lr = lane & 15;
    f32x4 acc[2];
    acc[0] = (f32x4){0.f, 0.f, 0.f, 0.f};
    acc[1] = (f32x4){0.f, 0.f, 0.f, 0.f};
#pragma unroll
    for (int kt = 0; kt < 4; ++kt) {
        short8 af = *(const short8*)&seg[(w * 16 + lr) * 136 + kt * 32 + quad * 8];
#pragma unroll
        for (int ni = 0; ni < 2; ++ni) {
            short8 bfr = *(const short8*)&w5s[(ni * 16 + lr) * 136 + kt * 32 + quad * 8];
            acc[ni] = __builtin_amdgcn_mfma_f32_16x16x32_bf16(af, bfr, acc[ni], 0, 0, 0);
        }
    }
#pragma unroll
    for (int ni = 0; ni < 2; ++ni) {
        int h = ni * 16 + lr;
#pragma unroll
        for (int r = 0; r < 4; ++r) {
            int cr = w * 16 + quad * 4 + r;
            float* ep = E + (size_t)(c0 + cr) * 32 + h;
            float v = acc[ni][r];
            if (g > 0) v += *ep;
            *ep = v;
        }
    }
}

// ---- output: out[h][cell] = occ ? relu(E[cell][h] + b5[h]) : 0 ----
__global__ __launch_bounds__(256) void out_kernel(
    const float* __restrict__ E, const int* __restrict__ cnt,
    const float* __restrict__ b5, float* __restrict__ out)
{
    int t = threadIdx.x;
    int c0 = blockIdx.x * 64;
    int lane = t & 63, hq = t >> 6;
    int cell = c0 + lane;
    if (c0 >= SEGR) {
#pragma unroll
        for (int j = 0; j < 8; ++j)
            out[(size_t)(hq * 8 + j) * NSEG + cell] = 0.f;
        return;
    }
    bool oc = cnt[cell] > 0;
    float4 e0 = *(const float4*)(E + (size_t)cell * 32 + hq * 8);
    float4 e1 = *(const float4*)(E + (size_t)cell * 32 + hq * 8 + 4);
    float r[8] = {e0.x, e0.y, e0.z, e0.w, e1.x, e1.y, e1.z, e1.w};
#pragma unroll
    for (int j = 0; j < 8; ++j) {
        float v = oc ? fmaxf(r[j] + b5[hq * 8 + j], 0.f) : 0.f;
        out[(size_t)(hq * 8 + j) * NSEG + cell] = v;
    }
}

extern "C" void kernel_launch(void* const* d_in, const int* in_sizes, int n_in,
                              void* d_out, int out_size, void* d_ws, size_t ws_size,
                              hipStream_t stream)
{
    const float* pt_fea = (const float*)d_in[0];
    const int*   xy_ind = (const int*)d_in[1];
    const float* bn0_g  = (const float*)d_in[2];
    const float* bn0_b  = (const float*)d_in[3];
    const float* W1     = (const float*)d_in[4];
    const float* b1     = (const float*)d_in[5];
    const float* bn1_g  = (const float*)d_in[6];
    const float* bn1_b  = (const float*)d_in[7];
    const float* W2     = (const float*)d_in[8];
    const float* b2     = (const float*)d_in[9];
    const float* bn2_g  = (const float*)d_in[10];
    const float* bn2_b  = (const float*)d_in[11];
    const float* W3     = (const float*)d_in[12];
    const float* b3     = (const float*)d_in[13];
    const float* bn3_g  = (const float*)d_in[14];
    const float* bn3_b  = (const float*)d_in[15];
    const float* W4     = (const float*)d_in[16];
    const float* b4     = (const float*)d_in[17];
    const float* W5     = (const float*)d_in[18];
    const float* b5     = (const float*)d_in[19];
    float* out = (float*)d_out;

    // ---- workspace layout (~111 MB, unchanged from R4..R10) ----
    const size_t oY2   = 61472768;                 // MPAD*256*2
    const size_t oE    = oY2 + (size_t)MPAD * 128 * 2;
    const size_t oCnt  = oE + (size_t)SEGR * 32 * 4;
    const size_t oOffs = oCnt + 518400;
    const size_t oCur  = oOffs + 518528;
    const size_t oOrd  = oCur + 518400;
    const size_t oCsum = oOrd + 480000;
    const size_t oSt   = oCsum + 512;
    const size_t oWt2  = oSt + 16384;
    const size_t oWt3  = oWt2 + 16384;
    const size_t oWt4  = oWt3 + 65536;
    const size_t oWt5  = oWt4 + 262144;

    unsigned short* y1   = (unsigned short*)d_ws;
    unsigned short* y3   = (unsigned short*)d_ws;
    unsigned short* y2   = (unsigned short*)((char*)d_ws + oY2);
    unsigned short* y4g  = (unsigned short*)((char*)d_ws + oY2);
    float*          E    = (float*)((char*)d_ws + oE);
    int*            cnt  = (int*)((char*)d_ws + oCnt);
    int*            offs = (int*)((char*)d_ws + oOffs);
    int*            cur  = (int*)((char*)d_ws + oCur);
    int*            ord  = (int*)((char*)d_ws + oOrd);
    int*            csum = (int*)((char*)d_ws + oCsum);
    float*          st   = (float*)((char*)d_ws + oSt);
    unsigned short* Wt2  = (unsigned short*)((char*)d_ws + oWt2);
    unsigned short* Wt3  = (unsigned short*)((char*)d_ws + oWt3);
    unsigned short* Wt4  = (unsigned short*)((char*)d_ws + oWt4);
    unsigned short* Wt5  = (unsigned short*)((char*)d_ws + oWt5);

    float* s0 = st + 0;     float* q0 = st + 8;
    float* W1p = st + 16;   float* b1p = st + 464;
    float* sum1 = st + 528; float* sq1 = st + 592; float* sc1 = st + 656; float* sh1 = st + 720;
    float* sum2 = st + 784; float* sq2 = st + 912; float* sc2 = st + 1040; float* sh2 = st + 1168;
    float* sum3 = st + 1296; float* sq3 = st + 1552; float* sc3 = st + 1808; float* sh3 = st + 2064;

    const int MB128 = MPAD / 128;   // 938

    wtrans_kernel<<<(64 * 128 + 255) / 256, 256, 0, stream>>>(W2, Wt2, 64, 128);
    wtrans_kernel<<<(128 * 256 + 255) / 256, 256, 0, stream>>>(W3, Wt3, 128, 256);
    wtrans_kernel<<<(256 * 512 + 255) / 256, 256, 0, stream>>>(W4, Wt4, 256, 512);
    wtrans_kernel<<<(512 * 32 + 255) / 256, 256, 0, stream>>>(W5, Wt5, 512, 32);

    for (int b = 0; b < 2; ++b) {
        const float* fea_b = pt_fea + (size_t)b * NPTS * 7;
        const int*   xy_b  = xy_ind + (size_t)b * NPTS * 2;
        float*       out_b = out + (size_t)b * NHD * NSEG;

        (void)hipMemsetAsync(st, 0, 2320 * sizeof(float), stream);
        (void)hipMemsetAsync(cnt, 0, (size_t)SEGR * 4, stream);

        bn0_stats_kernel<<<128, 256, 0, stream>>>(fea_b, s0, q0);
        prep0_kernel<<<1, 64, 0, stream>>>(s0, q0, bn0_g, bn0_b, W1, b1, W1p, b1p);
        layer1_kernel<<<MPAD / 256, 256, 0, stream>>>(fea_b, W1p, b1p, y1, sum1, sq1);
        prep_bn_kernel<<<1, 64, 0, stream>>>(sum1, sq1, bn1_g, bn1_b, sc1, sh1, 64);
        gemm_quad<64, 128, true><<<dim3(1, MB128), 256, 0, stream>>>(
            y1, Wt2, sc1, sh1, b2, y2, sum2, sq2);
        prep_bn_kernel<<<1, 128, 0, stream>>>(sum2, sq2, bn2_g, bn2_b, sc2, sh2, 128);
        gemm_quad<128, 256, true><<<dim3(2, MB128), 256, 0, stream>>>(
            y2, Wt3, sc2, sh2, b3, y3, sum3, sq3);
        prep_bn_kernel<<<1, 256, 0, stream>>>(sum3, sq3, bn3_g, bn3_b, sc3, sh3, 256);

        hist_kernel<<<(NPTS + 255) / 256, 256, 0, stream>>>(xy_b, cnt);
        scanA_kernel<<<64, 256, 0, stream>>>(cnt, csum);
        scanB_kernel<<<1, 64, 0, stream>>>(csum, offs);
        scanC_kernel<<<64, 256, 0, stream>>>(cnt, csum, offs, cur);
        scatter_idx_kernel<<<(NPTS + 255) / 256, 256, 0, stream>>>(xy_b, cur, ord);

        for (int g = 0; g < 4; ++g) {
            gemm_quad<256, 128, false><<<dim3(1, MB128), 256, 0, stream>>>(
                y3, Wt4 + (size_t)g * 128 * 256, sc3, sh3, b4 + g * 128, y4g,
                nullptr, nullptr);
            segmax_l5_kernel<<<SEGR / 64, 256, 0, stream>>>(y4g, Wt5, offs, ord, g, E);
        }
        out_kernel<<<NSEG / 64, 256, 0, stream>>>(E, cnt, b5, out_b);
    }
}

// Round 12
// 835.421 us; speedup vs baseline: 1.2476x; 1.0550x over previous
//
#include <hip/hip_runtime.h>
#include <cstdint>

#define GXD 480
#define GYD 360
#define NHD 32
#define NPTS 120000
#define MPAD 120064           // NPTS padded to multiple of 256 (469*256)
#define SEGR 129600           // 360*360 possible ids
#define NSEG (GXD*GYD)        // 172800
#define EPSB 1e-5f

using short8 = __attribute__((ext_vector_type(8))) short;   // 8 bf16 in 4 VGPRs
using f32x4  = __attribute__((ext_vector_type(4))) float;   // MFMA accumulator

// ---- bf16 helpers ----
__device__ __forceinline__ float bf2f(unsigned short u) {
    return __uint_as_float(((unsigned int)u) << 16);
}
__device__ __forceinline__ unsigned short f2bf(float f) {
    unsigned int u = __float_as_uint(f);
    u += 0x7fffu + ((u >> 16) & 1u);   // round-to-nearest-even
    return (unsigned short)(u >> 16);
}
__device__ __forceinline__ unsigned int bnrelu_pack(unsigned int wv, float sc0, float sh0,
                                                    float sc1, float sh1)
{
    float lo = fmaxf(fmaf(bf2f((unsigned short)(wv & 0xffffu)), sc0, sh0), 0.f);
    float hi = fmaxf(fmaf(bf2f((unsigned short)(wv >> 16)), sc1, sh1), 0.f);
    return (unsigned int)f2bf(lo) | ((unsigned int)f2bf(hi) << 16);
}
// bn+relu applied to an 8-element bf16 A-fragment (k-ascending)
__device__ __forceinline__ short8 bn_frag(short8 a, float4 s0, float4 s1,
                                          float4 h0, float4 h1)
{
    union { short8 v; uint4 u; } in, out;
    in.v = a;
    out.u.x = bnrelu_pack(in.u.x, s0.x, h0.x, s0.y, h0.y);
    out.u.y = bnrelu_pack(in.u.y, s0.z, h0.z, s0.w, h0.w);
    out.u.z = bnrelu_pack(in.u.z, s1.x, h1.x, s1.y, h1.y);
    out.u.w = bnrelu_pack(in.u.w, s1.z, h1.z, s1.w, h1.w);
    return out.v;
}

// ---- async global->LDS, 16B per lane (dest = wave-uniform base + lane*16) ----
__device__ __forceinline__ void async16(const unsigned short* g, unsigned short* l)
{
    __builtin_amdgcn_global_load_lds(
        (const __attribute__((address_space(1))) unsigned int*)g,
        (__attribute__((address_space(3))) unsigned int*)l, 16, 0, 0);
}

// ---- bn0 stats ----
__global__ __launch_bounds__(256) void bn0_stats_kernel(
    const float* __restrict__ fea, float* __restrict__ s0, float* __restrict__ q0)
{
    float s[7] = {0,0,0,0,0,0,0}, q[7] = {0,0,0,0,0,0,0};
    for (int p = blockIdx.x * 256 + threadIdx.x; p < NPTS; p += gridDim.x * 256) {
        const float* r = fea + (size_t)p * 7;
#pragma unroll
        for (int f = 0; f < 7; ++f) { float v = r[f]; s[f] += v; q[f] += v * v; }
    }
    __shared__ float red[256];
    int t = threadIdx.x;
#pragma unroll
    for (int f = 0; f < 7; ++f) {
        red[t] = s[f]; __syncthreads();
        for (int o = 128; o > 0; o >>= 1) {
            if (t < o) red[t] += red[t + o];
            __syncthreads();
        }
        if (t == 0) atomicAdd(&s0[f], red[0]);
        __syncthreads();
        red[t] = q[f]; __syncthreads();
        for (int o = 128; o > 0; o >>= 1) {
            if (t < o) red[t] += red[t + o];
            __syncthreads();
        }
        if (t == 0) atomicAdd(&q0[f], red[0]);
        __syncthreads();
    }
}

// ---- fold bn0 into W1 ----
__global__ void prep0_kernel(const float* __restrict__ s0, const float* __restrict__ q0,
                             const float* __restrict__ g0, const float* __restrict__ b0,
                             const float* __restrict__ W1, const float* __restrict__ b1,
                             float* __restrict__ W1p, float* __restrict__ b1p)
{
    __shared__ float sc[7], sh[7];
    int t = threadIdx.x;
    if (t < 7) {
        float m = s0[t] / (float)NPTS;
        float v = q0[t] / (float)NPTS - m * m;
        float inv = 1.0f / sqrtf(fmaxf(v, 0.f) + EPSB);
        sc[t] = g0[t] * inv;
        sh[t] = b0[t] - m * g0[t] * inv;
    }
    __syncthreads();
    if (t < 64) {
        float acc = b1[t];
#pragma unroll
        for (int f = 0; f < 7; ++f) {
            W1p[f * 64 + t] = W1[f * 64 + t] * sc[f];
            acc += sh[f] * W1[f * 64 + t];
        }
        b1p[t] = acc;
    }
}

__global__ void prep_bn_kernel(const float* __restrict__ sum, const float* __restrict__ sq,
                               const float* __restrict__ g, const float* __restrict__ b,
                               float* __restrict__ sc, float* __restrict__ sh, int C)
{
    int c = blockIdx.x * blockDim.x + threadIdx.x;
    if (c < C) {
        float m = sum[c] / (float)NPTS;
        float v = sq[c] / (float)NPTS - m * m;
        float inv = 1.0f / sqrtf(fmaxf(v, 0.f) + EPSB);
        sc[c] = g[c] * inv;
        sh[c] = b[c] - m * g[c] * inv;
    }
}

// ---- weight transpose+cast: Wt[n][k] = bf16(W[k][n]) ----
__global__ __launch_bounds__(256) void wtrans_kernel(const float* __restrict__ W,
                                                     unsigned short* __restrict__ Wt,
                                                     int K, int N)
{
    int i = blockIdx.x * 256 + threadIdx.x;
    if (i < K * N) {
        int k = i / N, n = i % N;
        Wt[(size_t)n * K + k] = f2bf(W[i]);
    }
}

// ---- layer 1 v2: y1(bf16) = fea @ W1' + b1' (K=7, Nc=64) + fp32 col stats ----
__global__ __launch_bounds__(256) void layer1_kernel(
    const float* __restrict__ fea, const float* __restrict__ W1p, const float* __restrict__ b1p,
    unsigned short* __restrict__ y1, float* __restrict__ sum1, float* __restrict__ sq1)
{
    __shared__ float Wl[448], bl[64];
    __shared__ float feaL[256 * 7];
    __shared__ float colsum[64], colsq[64];
    int t = threadIdx.x;
    int p0 = blockIdx.x * 256;
    for (int i = t; i < 448; i += 256) Wl[i] = W1p[i];
    if (t < 64) { bl[t] = b1p[t]; colsum[t] = 0.f; colsq[t] = 0.f; }
    int nval7 = (NPTS - p0) * 7;                 // valid feature words in this block
    for (int i = t; i < 256 * 7; i += 256)
        feaL[i] = (i < nval7) ? fea[(size_t)p0 * 7 + i] : 0.f;
    __syncthreads();
    int cg = t & 7, pt = t >> 3;                 // 8 col-groups x 32 point-threads
    float s[8] = {}, q[8] = {};
#pragma unroll
    for (int it = 0; it < 8; ++it) {
        int row = it * 32 + pt;
        bool valid = (p0 + row) < NPTS;
        float f[7];
#pragma unroll
        for (int ff = 0; ff < 7; ++ff) f[ff] = feaL[row * 7 + ff];
        float vj[8];
#pragma unroll
        for (int j = 0; j < 8; ++j) {
            int c = cg * 8 + j;
            float v = bl[c];
#pragma unroll
            for (int ff = 0; ff < 7; ++ff) v = fmaf(f[ff], Wl[ff * 64 + c], v);
            vj[j] = v;
            if (valid) { s[j] += v; q[j] += v * v; }
        }
        uint4 ow;
        ow.x = (unsigned int)f2bf(vj[0]) | ((unsigned int)f2bf(vj[1]) << 16);
        ow.y = (unsigned int)f2bf(vj[2]) | ((unsigned int)f2bf(vj[3]) << 16);
        ow.z = (unsigned int)f2bf(vj[4]) | ((unsigned int)f2bf(vj[5]) << 16);
        ow.w = (unsigned int)f2bf(vj[6]) | ((unsigned int)f2bf(vj[7]) << 16);
        *(uint4*)(y1 + (size_t)(p0 + row) * 64 + cg * 8) = ow;
    }
#pragma unroll
    for (int off = 8; off < 64; off <<= 1) {
#pragma unroll
        for (int j = 0; j < 8; ++j) {
            s[j] += __shfl_xor(s[j], off);
            q[j] += __shfl_xor(q[j], off);
        }
    }
    if ((t & 63) < 8) {                          // one leader per cg per wave
#pragma unroll
        for (int j = 0; j < 8; ++j) {
            atomicAdd(&colsum[cg * 8 + j], s[j]);
            atomicAdd(&colsq[cg * 8 + j], q[j]);
        }
    }
    __syncthreads();
    if (t < 64) {
        atomicAdd(&sum1[t], colsum[t]);
        atomicAdd(&sq1[t], colsq[t]);
    }
}

// ---- MFMA GEMM v9: quadrant wave-private, SOFTWARE-PIPELINED K-loop ----
// Next round's async16 loads issue right after this round's frags are in regs
// (slab free), overlapping load latency with bn_frag+MFMA. No barriers.
template<int K, int NC, bool STATS>
__global__ __launch_bounds__(256) void gemm_quad(
    const unsigned short* __restrict__ A, const unsigned short* __restrict__ Wt,
    const float* __restrict__ scale, const float* __restrict__ shift,
    const float* __restrict__ bias, unsigned short* __restrict__ Y,
    float* __restrict__ osum, float* __restrict__ osq)
{
    __shared__ __align__(16) unsigned short lds[4 * 4096];  // 8KB per wave
    __shared__ float scs[K], shs[K];
    __shared__ float colsum[128], colsq[128];
    int t = threadIdx.x;
    int w = t >> 6, ln = t & 63, quad = ln >> 4, lr = ln & 15;
    int wr = w >> 1, wc = w & 1;
    int mb = blockIdx.y * 128 + wr * 64;          // this wave's 64 rows
    int cb = blockIdx.x * 128 + wc * 64;          // this wave's 64 cols
    unsigned short* Aw = lds + w * 4096;          // [64][32] ushort
    unsigned short* Bw = Aw + 2048;

    for (int i = t; i < K; i += 256) { scs[i] = scale[i]; shs[i] = shift[i]; }
    if (STATS && t < 128) { colsum[t] = 0.f; colsq[t] = 0.f; }
    __syncthreads();                               // once, before K-loop

    const int grow4 = ln >> 2, koff = (ln & 3) * 8;
    f32x4 acc[4][4];
#pragma unroll
    for (int i = 0; i < 4; ++i)
#pragma unroll
        for (int j = 0; j < 4; ++j) acc[i][j] = (f32x4){0.f, 0.f, 0.f, 0.f};

    // prologue: round 0 loads in flight
#pragma unroll
    for (int i = 0; i < 4; ++i) {
        async16(A + (size_t)(mb + i * 16 + grow4) * K + koff, Aw + i * 512 + ln * 8);
        async16(Wt + (size_t)(cb + i * 16 + grow4) * K + koff, Bw + i * 512 + ln * 8);
    }

    for (int kt = 0; kt < K; kt += 32) {
        int k0 = kt + quad * 8;                    // this lane's A-frag k-base
        float4 s0 = *(const float4*)&scs[k0];
        float4 s1 = *(const float4*)&scs[k0 + 4];
        float4 h0 = *(const float4*)&shs[k0];
        float4 h1 = *(const float4*)&shs[k0 + 4];
        asm volatile("s_waitcnt vmcnt(0)" ::: "memory");   // this round's tiles in LDS
        short8 af[4], bfr[4];
#pragma unroll
        for (int mi = 0; mi < 4; ++mi)
            af[mi] = *(const short8*)&Aw[(mi * 16 + lr) * 32 + quad * 8];
#pragma unroll
        for (int ni = 0; ni < 4; ++ni)
            bfr[ni] = *(const short8*)&Bw[(ni * 16 + lr) * 32 + quad * 8];
        asm volatile("s_waitcnt lgkmcnt(0)" ::: "memory"); // frags in regs, slab free
        if (kt + 32 < K) {                         // next round's loads under compute
            int kn = kt + 32;
#pragma unroll
            for (int i = 0; i < 4; ++i) {
                async16(A + (size_t)(mb + i * 16 + grow4) * K + kn + koff,
                        Aw + i * 512 + ln * 8);
                async16(Wt + (size_t)(cb + i * 16 + grow4) * K + kn + koff,
                        Bw + i * 512 + ln * 8);
            }
        }
#pragma unroll
        for (int mi = 0; mi < 4; ++mi)
            af[mi] = bn_frag(af[mi], s0, s1, h0, h1);
#pragma unroll
        for (int mi = 0; mi < 4; ++mi)
#pragma unroll
            for (int ni = 0; ni < 4; ++ni)
                acc[mi][ni] = __builtin_amdgcn_mfma_f32_16x16x32_bf16(
                    af[mi], bfr[ni], acc[mi][ni], 0, 0, 0);
    }

    // wave-private epilogue: C-stage 64x64 bf16 in own slab, no barriers
    asm volatile("s_waitcnt vmcnt(0)" ::: "memory");       // quiesce (none outstanding)
    unsigned short* Cw = Aw;
    // C/D layout: col=lane&15, row=quad*4+reg
#pragma unroll
    for (int ni = 0; ni < 4; ++ni) {
        int col = ni * 16 + lr;
        float bv = bias[cb + col];
        float s = 0.f, q = 0.f;
#pragma unroll
        for (int mi = 0; mi < 4; ++mi) {
            int rb = mi * 16 + quad * 4;
#pragma unroll
            for (int r = 0; r < 4; ++r) {
                float v = acc[mi][ni][r] + bv;
                Cw[(rb + r) * 64 + col] = f2bf(v);
                if (STATS && (mb + rb + r) < NPTS) { s += v; q += v * v; }
            }
        }
        if (STATS) {
            atomicAdd(&colsum[wc * 64 + col], s);
            atomicAdd(&colsq[wc * 64 + col], q);
        }
    }
#pragma unroll
    for (int i = 0; i < 8; ++i) {                  // 64x64 tile, full-line uint4 stores
        int idx = i * 64 + ln;
        int row = idx >> 3, colq = (idx & 7) * 8;
        *(uint4*)(Y + (size_t)(mb + row) * NC + cb + colq) = *(const uint4*)&Cw[row * 64 + colq];
    }
    if (STATS) {
        __syncthreads();                           // once, after all waves' LDS atomics
        if (t < 128) {
            atomicAdd(&osum[blockIdx.x * 128 + t], colsum[t]);
            atomicAdd(&osq[blockIdx.x * 128 + t], colsq[t]);
        }
    }
}

// ---- sort machinery: histogram, 3-phase exclusive scan, index scatter ----
__global__ __launch_bounds__(256) void hist_kernel(const int* __restrict__ xy,
                                                   int* __restrict__ cnt)
{
    int p = blockIdx.x * 256 + threadIdx.x;
    if (p < NPTS) {
        int id = xy[(size_t)p * 2] * GYD + xy[(size_t)p * 2 + 1];
        atomicAdd(&cnt[id], 1);
    }
}

__global__ __launch_bounds__(256) void scanA_kernel(const int* __restrict__ cnt,
                                                    int* __restrict__ csum)
{
    __shared__ int red[256];
    int t = threadIdx.x, base = blockIdx.x * 2048;
    int s = 0;
    for (int i = t; i < 2048; i += 256) {
        int idx = base + i;
        if (idx < SEGR) s += cnt[idx];
    }
    red[t] = s; __syncthreads();
    for (int o = 128; o > 0; o >>= 1) { if (t < o) red[t] += red[t + o]; __syncthreads(); }
    if (t == 0) csum[blockIdx.x] = red[0];
}

__global__ void scanB_kernel(int* __restrict__ csum, int* __restrict__ offs)
{
    if (threadIdx.x == 0) {
        int run = 0;
        for (int i = 0; i < 64; ++i) { int v = csum[i]; csum[i] = run; run += v; }
        offs[SEGR] = run;
    }
}

__global__ __launch_bounds__(256) void scanC_kernel(const int* __restrict__ cnt,
                                                    const int* __restrict__ csum,
                                                    int* __restrict__ offs,
                                                    int* __restrict__ cursor)
{
    __shared__ int red[256];
    int t = threadIdx.x, base = blockIdx.x * 2048;
    int v[8]; int s = 0;
#pragma unroll
    for (int i = 0; i < 8; ++i) {
        int idx = base + t * 8 + i;
        v[i] = (idx < SEGR) ? cnt[idx] : 0;
        s += v[i];
    }
    red[t] = s; __syncthreads();
    for (int o = 1; o < 256; o <<= 1) {
        int x = (t >= o) ? red[t - o] : 0;
        __syncthreads();
        red[t] += x;
        __syncthreads();
    }
    int run = red[t] - s + csum[blockIdx.x];
#pragma unroll
    for (int i = 0; i < 8; ++i) {
        int idx = base + t * 8 + i;
        if (idx < SEGR) { offs[idx] = run; cursor[idx] = run; }
        run += v[i];
    }
}

__global__ __launch_bounds__(256) void scatter_idx_kernel(const int* __restrict__ xy,
                                                          int* __restrict__ cursor,
                                                          int* __restrict__ order)
{
    int p = blockIdx.x * 256 + threadIdx.x;
    if (p < NPTS) {
        int id = xy[(size_t)p * 2] * GYD + xy[(size_t)p * 2 + 1];
        int pos = atomicAdd(&cursor[id], 1);
        order[pos] = p;
    }
}

// ---- fused gather-segmax + partial L5: E[cell][32] (+)= max_pts(y4g) @ W5[g-slice] ----
__global__ __launch_bounds__(256) void segmax_l5_kernel(
    const unsigned short* __restrict__ y4g, const unsigned short* __restrict__ Wt5,
    const int* __restrict__ offs, const int* __restrict__ order,
    int g, float* __restrict__ E)
{
    __shared__ __align__(16) unsigned short seg[64 * 136];
    __shared__ __align__(16) unsigned short w5s[32 * 136];
    __shared__ int offs_s[65];
    int t = threadIdx.x;
    int c0 = blockIdx.x * 64;
    if (t < 65) offs_s[t] = offs[c0 + t];
    {   // stage Wt5[n=0..31][k = g*128 .. +128]
        int n = t >> 3, ko = (t & 7) * 16;
        *(uint4*)&w5s[n * 136 + ko]     = *(const uint4*)(Wt5 + (size_t)n * 512 + g * 128 + ko);
        *(uint4*)&w5s[n * 136 + ko + 8] = *(const uint4*)(Wt5 + (size_t)n * 512 + g * 128 + ko + 8);
    }
    __syncthreads();
    int cell = t >> 2, q = t & 3;
    float mx[32];
#pragma unroll
    for (int i = 0; i < 32; ++i) mx[i] = -3.0e38f;
    int jb = offs_s[cell], je = offs_s[cell + 1];
    for (int j = jb; j < je; ++j) {
        int p = order[j];
        const uint4* rp = (const uint4*)(y4g + (size_t)p * 128 + q * 32);
#pragma unroll
        for (int u = 0; u < 4; ++u) {
            uint4 vv = rp[u];
            unsigned int wv[4] = {vv.x, vv.y, vv.z, vv.w};
#pragma unroll
            for (int k2 = 0; k2 < 4; ++k2) {
                int idx = u * 8 + k2 * 2;
                mx[idx]     = fmaxf(mx[idx],     bf2f((unsigned short)(wv[k2] & 0xffffu)));
                mx[idx + 1] = fmaxf(mx[idx + 1], bf2f((unsigned short)(wv[k2] >> 16)));
            }
        }
    }
    bool empty = (jb == je);
#pragma unroll
    for (int i = 0; i < 16; ++i) {
        float lo = empty ? 0.f : mx[2 * i], hi = empty ? 0.f : mx[2 * i + 1];
        unsigned int pk = (unsigned int)f2bf(lo) | ((unsigned int)f2bf(hi) << 16);
        *(unsigned int*)&seg[cell * 136 + q * 32 + 2 * i] = pk;
    }
    __syncthreads();
    int lane = t & 63, w = t >> 6, quad = lane >> 4, lr = lane & 15;
    f32x4 acc[2];
    acc[0] = (f32x4){0.f, 0.f, 0.f, 0.f};
    acc[1] = (f32x4){0.f, 0.f, 0.f, 0.f};
#pragma unroll
    for (int kt = 0; kt < 4; ++kt) {
        short8 af = *(const short8*)&seg[(w * 16 + lr) * 136 + kt * 32 + quad * 8];
#pragma unroll
        for (int ni = 0; ni < 2; ++ni) {
            short8 bfr = *(const short8*)&w5s[(ni * 16 + lr) * 136 + kt * 32 + quad * 8];
            acc[ni] = __builtin_amdgcn_mfma_f32_16x16x32_bf16(af, bfr, acc[ni], 0, 0, 0);
        }
    }
#pragma unroll
    for (int ni = 0; ni < 2; ++ni) {
        int h = ni * 16 + lr;
#pragma unroll
        for (int r = 0; r < 4; ++r) {
            int cr = w * 16 + quad * 4 + r;
            float* ep = E + (size_t)(c0 + cr) * 32 + h;
            float v = acc[ni][r];
            if (g > 0) v += *ep;
            *ep = v;
        }
    }
}

// ---- output: out[h][cell] = occ ? relu(E[cell][h] + b5[h]) : 0 ----
__global__ __launch_bounds__(256) void out_kernel(
    const float* __restrict__ E, const int* __restrict__ cnt,
    const float* __restrict__ b5, float* __restrict__ out)
{
    int t = threadIdx.x;
    int c0 = blockIdx.x * 64;
    int lane = t & 63, hq = t >> 6;
    int cell = c0 + lane;
    if (c0 >= SEGR) {
#pragma unroll
        for (int j = 0; j < 8; ++j)
            out[(size_t)(hq * 8 + j) * NSEG + cell] = 0.f;
        return;
    }
    bool oc = cnt[cell] > 0;
    float4 e0 = *(const float4*)(E + (size_t)cell * 32 + hq * 8);
    float4 e1 = *(const float4*)(E + (size_t)cell * 32 + hq * 8 + 4);
    float r[8] = {e0.x, e0.y, e0.z, e0.w, e1.x, e1.y, e1.z, e1.w};
#pragma unroll
    for (int j = 0; j < 8; ++j) {
        float v = oc ? fmaxf(r[j] + b5[hq * 8 + j], 0.f) : 0.f;
        out[(size_t)(hq * 8 + j) * NSEG + cell] = v;
    }
}

extern "C" void kernel_launch(void* const* d_in, const int* in_sizes, int n_in,
                              void* d_out, int out_size, void* d_ws, size_t ws_size,
                              hipStream_t stream)
{
    const float* pt_fea = (const float*)d_in[0];
    const int*   xy_ind = (const int*)d_in[1];
    const float* bn0_g  = (const float*)d_in[2];
    const float* bn0_b  = (const float*)d_in[3];
    const float* W1     = (const float*)d_in[4];
    const float* b1     = (const float*)d_in[5];
    const float* bn1_g  = (const float*)d_in[6];
    const float* bn1_b  = (const float*)d_in[7];
    const float* W2     = (const float*)d_in[8];
    const float* b2     = (const float*)d_in[9];
    const float* bn2_g  = (const float*)d_in[10];
    const float* bn2_b  = (const float*)d_in[11];
    const float* W3     = (const float*)d_in[12];
    const float* b3     = (const float*)d_in[13];
    const float* bn3_g  = (const float*)d_in[14];
    const float* bn3_b  = (const float*)d_in[15];
    const float* W4     = (const float*)d_in[16];
    const float* b4     = (const float*)d_in[17];
    const float* W5     = (const float*)d_in[18];
    const float* b5     = (const float*)d_in[19];
    float* out = (float*)d_out;

    // ---- workspace layout (~111 MB, unchanged from R4..R11) ----
    const size_t oY2   = 61472768;                 // MPAD*256*2
    const size_t oE    = oY2 + (size_t)MPAD * 128 * 2;
    const size_t oCnt  = oE + (size_t)SEGR * 32 * 4;
    const size_t oOffs = oCnt + 518400;
    const size_t oCur  = oOffs + 518528;
    const size_t oOrd  = oCur + 518400;
    const size_t oCsum = oOrd + 480000;
    const size_t oSt   = oCsum + 512;
    const size_t oWt2  = oSt + 16384;
    const size_t oWt3  = oWt2 + 16384;
    const size_t oWt4  = oWt3 + 65536;
    const size_t oWt5  = oWt4 + 262144;

    unsigned short* y1   = (unsigned short*)d_ws;
    unsigned short* y3   = (unsigned short*)d_ws;
    unsigned short* y2   = (unsigned short*)((char*)d_ws + oY2);
    unsigned short* y4g  = (unsigned short*)((char*)d_ws + oY2);
    float*          E    = (float*)((char*)d_ws + oE);
    int*            cnt  = (int*)((char*)d_ws + oCnt);
    int*            offs = (int*)((char*)d_ws + oOffs);
    int*            cur  = (int*)((char*)d_ws + oCur);
    int*            ord  = (int*)((char*)d_ws + oOrd);
    int*            csum = (int*)((char*)d_ws + oCsum);
    float*          st   = (float*)((char*)d_ws + oSt);
    unsigned short* Wt2  = (unsigned short*)((char*)d_ws + oWt2);
    unsigned short* Wt3  = (unsigned short*)((char*)d_ws + oWt3);
    unsigned short* Wt4  = (unsigned short*)((char*)d_ws + oWt4);
    unsigned short* Wt5  = (unsigned short*)((char*)d_ws + oWt5);

    float* s0 = st + 0;     float* q0 = st + 8;
    float* W1p = st + 16;   float* b1p = st + 464;
    float* sum1 = st + 528; float* sq1 = st + 592; float* sc1 = st + 656; float* sh1 = st + 720;
    float* sum2 = st + 784; float* sq2 = st + 912; float* sc2 = st + 1040; float* sh2 = st + 1168;
    float* sum3 = st + 1296; float* sq3 = st + 1552; float* sc3 = st + 1808; float* sh3 = st + 2064;

    const int MB128 = MPAD / 128;   // 938

    wtrans_kernel<<<(64 * 128 + 255) / 256, 256, 0, stream>>>(W2, Wt2, 64, 128);
    wtrans_kernel<<<(128 * 256 + 255) / 256, 256, 0, stream>>>(W3, Wt3, 128, 256);
    wtrans_kernel<<<(256 * 512 + 255) / 256, 256, 0, stream>>>(W4, Wt4, 256, 512);
    wtrans_kernel<<<(512 * 32 + 255) / 256, 256, 0, stream>>>(W5, Wt5, 512, 32);

    for (int b = 0; b < 2; ++b) {
        const float* fea_b = pt_fea + (size_t)b * NPTS * 7;
        const int*   xy_b  = xy_ind + (size_t)b * NPTS * 2;
        float*       out_b = out + (size_t)b * NHD * NSEG;

        (void)hipMemsetAsync(st, 0, 2320 * sizeof(float), stream);
        (void)hipMemsetAsync(cnt, 0, (size_t)SEGR * 4, stream);

        bn0_stats_kernel<<<128, 256, 0, stream>>>(fea_b, s0, q0);
        prep0_kernel<<<1, 64, 0, stream>>>(s0, q0, bn0_g, bn0_b, W1, b1, W1p, b1p);
        layer1_kernel<<<MPAD / 256, 256, 0, stream>>>(fea_b, W1p, b1p, y1, sum1, sq1);
        prep_bn_kernel<<<1, 64, 0, stream>>>(sum1, sq1, bn1_g, bn1_b, sc1, sh1, 64);
        gemm_quad<64, 128, true><<<dim3(1, MB128), 256, 0, stream>>>(
            y1, Wt2, sc1, sh1, b2, y2, sum2, sq2);
        prep_bn_kernel<<<1, 128, 0, stream>>>(sum2, sq2, bn2_g, bn2_b, sc2, sh2, 128);
        gemm_quad<128, 256, true><<<dim3(2, MB128), 256, 0, stream>>>(
            y2, Wt3, sc2, sh2, b3, y3, sum3, sq3);
        prep_bn_kernel<<<1, 256, 0, stream>>>(sum3, sq3, bn3_g, bn3_b, sc3, sh3, 256);

        hist_kernel<<<(NPTS + 255) / 256, 256, 0, stream>>>(xy_b, cnt);
        scanA_kernel<<<64, 256, 0, stream>>>(cnt, csum);
        scanB_kernel<<<1, 64, 0, stream>>>(csum, offs);
        scanC_kernel<<<64, 256, 0, stream>>>(cnt, csum, offs, cur);
        scatter_idx_kernel<<<(NPTS + 255) / 256, 256, 0, stream>>>(xy_b, cur, ord);

        for (int g = 0; g < 4; ++g) {
            gemm_quad<256, 128, false><<<dim3(1, MB128), 256, 0, stream>>>(
                y3, Wt4 + (size_t)g * 128 * 256, sc3, sh3, b4 + g * 128, y4g,
                nullptr, nullptr);
            segmax_l5_kernel<<<SEGR / 64, 256, 0, stream>>>(y4g, Wt5, offs, ord, g, E);
        }
        out_kernel<<<NSEG / 64, 256, 0, stream>>>(E, cnt, b5, out_b);
    }
}